// Round 4
// baseline (543.417 us; speedup 1.0000x reference)
//
#include <hip/hip_runtime.h>
#include <hip/hip_bf16.h>

#define BSZ 16
#define TT 4096
#define UU 128
#define OO 128
#define SS 256
#define HH 512
#define BT (BSZ*TT)      // 65536 rows
#define CLEN 64          // scan chunk length
#define NCH (TT/CLEN)    // 64 chunks per sequence

using bf16x8 = __attribute__((ext_vector_type(8))) short;
using f32x4  = __attribute__((ext_vector_type(4))) float;

__device__ __forceinline__ unsigned short f2bf(float x){
  union { float f; unsigned int u; } v; v.f = x;
  unsigned int r = v.u + 0x7fffu + ((v.u >> 16) & 1u);
  return (unsigned short)(r >> 16);
}
__device__ __forceinline__ float bf2f(unsigned short h){
  union { float f; unsigned int u; } v; v.u = ((unsigned int)h) << 16;
  return v.f;
}

// async global->LDS, 16B per lane (linear dest; source carries the swizzle)
#define GLD16(g, s) __builtin_amdgcn_global_load_lds( \
    (const __attribute__((address_space(1))) unsigned int*)(g), \
    (__attribute__((address_space(3))) unsigned int*)(s), 16, 0, 0)

// ---------------- split fp32 -> (hi, lo) bf16 planes ----------------
__global__ __launch_bounds__(256) void split_k(const float* __restrict__ x,
                                               unsigned short* __restrict__ H,
                                               unsigned short* __restrict__ L, int n4){
  int i = blockIdx.x * 256 + threadIdx.x;
  if (i >= n4) return;
  float4 v = ((const float4*)x)[i];
  unsigned short h0 = f2bf(v.x), h1 = f2bf(v.y), h2 = f2bf(v.z), h3 = f2bf(v.w);
  ushort4 hh = make_ushort4(h0, h1, h2, h3);
  ushort4 ll = make_ushort4(f2bf(v.x - bf2f(h0)), f2bf(v.y - bf2f(h1)),
                            f2bf(v.z - bf2f(h2)), f2bf(v.w - bf2f(h3)));
  ((ushort4*)H)[i] = hh;
  ((ushort4*)L)[i] = ll;
}

// ---------------- K-segmented single-plane MFMA GEMM ----------------
// C[M][Nout] = sum over segments s of A_s * B_s^T.  Split precision is
// expressed as segments: (Ah,Bh),(Al,Bh),(Ah,Bl) per source.
// BM=256, BN=128, BK=64, 512 threads (8 waves as 4x2), 3-deep LDS ring,
// counted vmcnt(6) + raw s_barrier (loads span barriers), setprio on MFMA.
struct SegDesc {
  const unsigned short* a[6];
  const unsigned short* b[6];
  int tiles[6];    // K-tiles (of 64) per segment; 0 = unused
  int stride[6];   // row stride (elements) of that segment's sources
};

__global__ __launch_bounds__(512, 1) void gemm8(SegDesc sd, int NT,
    unsigned short* __restrict__ outH, unsigned short* __restrict__ outL,
    float* __restrict__ outF, int Nout, int EPI, int gx)
{
  __shared__ __align__(16) unsigned short As[3][256*64];   // 96 KB
  __shared__ __align__(16) unsigned short Bs[3][128*64];   // 48 KB

  const int tid = threadIdx.x;
  const int l = tid & 63, w = tid >> 6;
  const int wr = w >> 1, wc = w & 1;        // 4x2 wave grid, per-wave 64x64
  const int fr = l & 15, fq = l >> 4;

  // XCD-chunked swizzle (nwg % 8 == 0 for all our grids), nb-fastest so
  // consecutive work-ids share the A row-panel within an XCD's L2.
  const int nwg = gridDim.x;
  const int bid = blockIdx.x;
  const int q8 = nwg >> 3;
  const int swz = (bid & 7) * q8 + (bid >> 3);
  const int nb = swz % gx;
  const int mb = swz / gx;

  auto STAGE = [&](int kt, int buf){
    const unsigned short* ap = sd.a[0];
    const unsigned short* bp = sd.b[0];
    int st = sd.stride[0], kb = 0, cum = 0;
    #pragma unroll
    for (int s = 0; s < 6; s++){
      int t = sd.tiles[s];
      if (kt >= cum && kt < cum + t){ ap = sd.a[s]; bp = sd.b[s]; st = sd.stride[s]; kb = cum; }
      cum += t;
    }
    const int kk = (kt - kb) << 6;
    // A tile: 256 rows x 64 cols bf16 = 2048 16B-segs; inverse-swizzled source
    #pragma unroll
    for (int i = 0; i < 4; i++){
      int seg = tid + (i << 9);
      int r = seg >> 3, c = seg & 7;
      int sc = (c ^ (r & 7)) << 3;
      GLD16(ap + (size_t)(mb*256 + r) * st + kk + sc, &As[buf][seg*8]);
    }
    // B tile: 128 rows x 64 cols = 1024 segs
    #pragma unroll
    for (int i = 0; i < 2; i++){
      int seg = tid + (i << 9);
      int r = seg >> 3, c = seg & 7;
      int sc = (c ^ (r & 7)) << 3;
      GLD16(bp + (size_t)(nb*128 + r) * st + kk + sc, &Bs[buf][seg*8]);
    }
  };

  f32x4 acc[4][4];
  #pragma unroll
  for (int m = 0; m < 4; m++)
    #pragma unroll
    for (int n = 0; n < 4; n++) acc[m][n] = f32x4{0.f, 0.f, 0.f, 0.f};

  STAGE(0, 0);
  STAGE(1, 1);

  for (int kt = 0; kt < NT; kt++){
    if (kt + 1 < NT) asm volatile("s_waitcnt vmcnt(6)" ::: "memory");
    else             asm volatile("s_waitcnt vmcnt(0)" ::: "memory");
    __builtin_amdgcn_sched_barrier(0);
    __builtin_amdgcn_s_barrier();
    if (kt + 2 < NT) STAGE(kt + 2, (kt + 2) % 3);   // targets buffer freed at kt-1

    const unsigned short* A = As[kt % 3];
    const unsigned short* B = Bs[kt % 3];
    bf16x8 af[2][4], bfr[2][4];
    #pragma unroll
    for (int ks = 0; ks < 2; ks++){
      const int cb = ks*4 + fq;
      #pragma unroll
      for (int m = 0; m < 4; m++){
        int r = wr*64 + m*16 + fr;
        af[ks][m] = *(const bf16x8*)&A[r*64 + ((cb ^ (r & 7)) << 3)];
      }
      #pragma unroll
      for (int n = 0; n < 4; n++){
        int r = wc*64 + n*16 + fr;
        bfr[ks][n] = *(const bf16x8*)&B[r*64 + ((cb ^ (r & 7)) << 3)];
      }
    }
    __builtin_amdgcn_s_setprio(1);
    #pragma unroll
    for (int ks = 0; ks < 2; ks++)
      #pragma unroll
      for (int m = 0; m < 4; m++)
        #pragma unroll
        for (int n = 0; n < 4; n++)
          acc[m][n] = __builtin_amdgcn_mfma_f32_16x16x32_bf16(af[ks][m], bfr[ks][n], acc[m][n], 0, 0, 0);
    __builtin_amdgcn_s_setprio(0);
  }

  #pragma unroll
  for (int m = 0; m < 4; m++){
    int rowb = mb*256 + wr*64 + m*16 + fq*4;
    #pragma unroll
    for (int n = 0; n < 4; n++){
      int col = nb*128 + wc*64 + n*16 + fr;
      #pragma unroll
      for (int j = 0; j < 4; j++){
        float x = acc[m][n][j];
        size_t o = (size_t)(rowb + j) * Nout + col;
        if (EPI == 0){
          outF[o] = x;
        } else {
          if (EPI == 2)      x = x / (1.f + __expf(-x));   // silu
          else if (EPI == 3) x = fmaxf(x, 0.f);            // relu
          unsigned short h = f2bf(x);
          outH[o] = h;
          outL[o] = f2bf(x - bf2f(h));
        }
      }
    }
  }
}

// ---------------- scan phase 1: per-chunk end state (h0 = 0) ----------------
__global__ __launch_bounds__(256) void scan_ends(const float* __restrict__ bu,
                                                 const float* __restrict__ lre,
                                                 const float* __restrict__ lim,
                                                 float2* __restrict__ ends){
  const int s = threadIdx.x;
  const int b = blockIdx.x >> 6;
  const int c = blockIdx.x & 63;
  const float lr = lre[s], li = lim[s];
  float hr = 0.f, hi = 0.f;
  const float* p = bu + ((size_t)b*TT + (size_t)c*CLEN)*SS + s;
  #pragma unroll 8
  for (int t = 0; t < CLEN; t++){
    float x  = p[(size_t)t * SS];
    float nr = fmaf(lr, hr, fmaf(-li, hi, x));
    float ni = fmaf(lr, hi, li * hr);
    hr = nr; hi = ni;
  }
  ends[((size_t)b*NCH + c)*SS + s] = make_float2(hr, hi);
}

// ---------------- scan phase 2: carry scan across chunks ----------------
__global__ __launch_bounds__(256) void scan_carries(const float2* __restrict__ ends,
                                                    const float* __restrict__ lre,
                                                    const float* __restrict__ lim,
                                                    float2* __restrict__ carryin){
  const int idx = blockIdx.x * 256 + threadIdx.x;   // over B*S = 4096
  const int b = idx >> 8;
  const int s = idx & 255;
  float pr = lre[s], pi = lim[s];
  #pragma unroll
  for (int q = 0; q < 6; q++){      // lam^64 by squaring
    float nr = pr*pr - pi*pi;
    float ni = 2.f * pr * pi;
    pr = nr; pi = ni;
  }
  float hr = 0.f, hi = 0.f;
  for (int c = 0; c < NCH; c++){
    size_t o = ((size_t)b*NCH + c)*SS + s;
    carryin[o] = make_float2(hr, hi);
    float2 e = ends[o];
    float nr = fmaf(pr, hr, fmaf(-pi, hi, e.x));
    float ni = fmaf(pr, hi, fmaf(pi, hr, e.y));
    hr = nr; hi = ni;
  }
}

// ---------------- scan phase 3: replay chunk, write Re(h) split planes ----------------
__global__ __launch_bounds__(256) void scan_apply(const float* __restrict__ bu,
                                                  const float* __restrict__ lre,
                                                  const float* __restrict__ lim,
                                                  const float2* __restrict__ carryin,
                                                  unsigned short* __restrict__ RehH,
                                                  unsigned short* __restrict__ RehL){
  const int s = threadIdx.x;
  const int b = blockIdx.x >> 6;
  const int c = blockIdx.x & 63;
  const float lr = lre[s], li = lim[s];
  float2 h0 = carryin[((size_t)b*NCH + c)*SS + s];
  float hr = h0.x, hi = h0.y;
  const size_t base = ((size_t)b*TT + (size_t)c*CLEN)*SS + s;
  #pragma unroll 4
  for (int t = 0; t < CLEN; t++){
    float x  = bu[base + (size_t)t * SS];
    float nr = fmaf(lr, hr, fmaf(-li, hi, x));
    float ni = fmaf(lr, hi, li * hr);
    hr = nr; hi = ni;
    unsigned short h = f2bf(hr);
    RehH[base + (size_t)t * SS] = h;
    RehL[base + (size_t)t * SS] = f2bf(hr - bf2f(h));
  }
}

// ---------------- host-side segment builder ----------------
static void seg_clear(SegDesc& sd){
  for (int i = 0; i < 6; i++){ sd.a[i]=nullptr; sd.b[i]=nullptr; sd.tiles[i]=0; sd.stride[i]=0; }
}
static int seg_add3(SegDesc& sd, int at,
                    const unsigned short* aH, const unsigned short* aL,
                    const unsigned short* bH, const unsigned short* bL, int K){
  int t = K >> 6;
  sd.a[at+0]=aH; sd.b[at+0]=bH; sd.tiles[at+0]=t; sd.stride[at+0]=K;
  sd.a[at+1]=aL; sd.b[at+1]=bH; sd.tiles[at+1]=t; sd.stride[at+1]=K;
  sd.a[at+2]=aH; sd.b[at+2]=bL; sd.tiles[at+2]=t; sd.stride[at+2]=K;
  return 3*t;
}

extern "C" void kernel_launch(void* const* d_in, const int* in_sizes, int n_in,
                              void* d_out, int out_size, void* d_ws, size_t ws_size,
                              hipStream_t stream){
  const float* inp = (const float*)d_in[0];
  const float* lre = (const float*)d_in[1];
  const float* lim = (const float*)d_in[2];
  const float* Bm  = (const float*)d_in[3];
  const float* Cm  = (const float*)d_in[4];
  const float* Dm  = (const float*)d_in[5];
  const float* W1  = (const float*)d_in[6];
  const float* W2  = (const float*)d_in[7];
  const float* W3  = (const float*)d_in[8];
  const float* Wl  = (const float*)d_in[9];
  float* out = (float*)d_out;

  char* ws = (char*)d_ws;
  size_t off = 0;
  auto alloc = [&](size_t bytes)->char*{
    char* p = ws + off; off += (bytes + 255) & ~(size_t)255; return p;
  };
  unsigned short* inH = (unsigned short*)alloc((size_t)BT*UU*2);
  unsigned short* inL = (unsigned short*)alloc((size_t)BT*UU*2);
  unsigned short* BwH = (unsigned short*)alloc((size_t)SS*UU*2);
  unsigned short* BwL = (unsigned short*)alloc((size_t)SS*UU*2);
  unsigned short* CH_ = (unsigned short*)alloc((size_t)OO*SS*2);
  unsigned short* CL_ = (unsigned short*)alloc((size_t)OO*SS*2);
  unsigned short* DH_ = (unsigned short*)alloc((size_t)OO*UU*2);
  unsigned short* DL_ = (unsigned short*)alloc((size_t)OO*UU*2);
  unsigned short* W1H = (unsigned short*)alloc((size_t)HH*OO*2);
  unsigned short* W1L = (unsigned short*)alloc((size_t)HH*OO*2);
  unsigned short* W2H = (unsigned short*)alloc((size_t)HH*HH*2);
  unsigned short* W2L = (unsigned short*)alloc((size_t)HH*HH*2);
  unsigned short* W3H = (unsigned short*)alloc((size_t)OO*HH*2);
  unsigned short* W3L = (unsigned short*)alloc((size_t)OO*HH*2);
  unsigned short* WlH = (unsigned short*)alloc((size_t)OO*UU*2);
  unsigned short* WlL = (unsigned short*)alloc((size_t)OO*UU*2);
  float2* ends    = (float2*)alloc((size_t)BSZ*NCH*SS*8);
  float2* carryin = (float2*)alloc((size_t)BSZ*NCH*SS*8);
  char* R1 = alloc((size_t)BT*SS*4);     // 64 MB: bu -> z1(hi plane or halved hi+lo)
  char* R2 = alloc((size_t)BT*SS*4);     // 64 MB: Reh planes -> z1 lo / z2
  unsigned short* yH = (unsigned short*)alloc((size_t)BT*OO*2);
  unsigned short* yL = (unsigned short*)alloc((size_t)BT*OO*2);
  if (off > ws_size) return;

  float* bu = (float*)R1;
  unsigned short* RehH = (unsigned short*)R2;
  unsigned short* RehL = (unsigned short*)(R2 + (size_t)BT*SS*2);

  // full-M MLP path needs one extra 128 MB region for z2 (z1 reuses R1+R2,
  // which are contiguous). Fall back to batch-halved if ws is too small.
  bool full = false;
  char* z2reg = nullptr;
  {
    size_t need = off + (size_t)BT*HH*2*2;
    if (need <= ws_size){ z2reg = alloc((size_t)BT*HH*2*2); full = true; }
  }

  // ---- split input + weights into bf16 hi/lo planes ----
  split_k<<<(BT*UU/4 + 255)/256, 256, 0, stream>>>(inp, inH, inL, BT*UU/4);
  split_k<<<(SS*UU/4 + 255)/256, 256, 0, stream>>>(Bm, BwH, BwL, SS*UU/4);
  split_k<<<(OO*SS/4 + 255)/256, 256, 0, stream>>>(Cm, CH_, CL_, OO*SS/4);
  split_k<<<(OO*UU/4 + 255)/256, 256, 0, stream>>>(Dm, DH_, DL_, OO*UU/4);
  split_k<<<(HH*OO/4 + 255)/256, 256, 0, stream>>>(W1, W1H, W1L, HH*OO/4);
  split_k<<<(HH*HH/4 + 255)/256, 256, 0, stream>>>(W2, W2H, W2L, HH*HH/4);
  split_k<<<(OO*HH/4 + 255)/256, 256, 0, stream>>>(W3, W3H, W3L, OO*HH/4);
  split_k<<<(OO*UU/4 + 255)/256, 256, 0, stream>>>(Wl, WlH, WlL, OO*UU/4);

  SegDesc sd; int NT;

  // ---- bu = input @ B^T (fp32 out for the scan) ----
  seg_clear(sd); NT = seg_add3(sd, 0, inH, inL, BwH, BwL, UU);
  gemm8<<<(BT/256)*(SS/128), 512, 0, stream>>>(sd, NT, nullptr, nullptr, bu, SS, 0, SS/128);

  // ---- diagonal complex scan ----
  scan_ends<<<BSZ*NCH, 256, 0, stream>>>(bu, lre, lim, ends);
  scan_carries<<<(BSZ*SS)/256, 256, 0, stream>>>(ends, lre, lim, carryin);
  scan_apply<<<BSZ*NCH, 256, 0, stream>>>(bu, lre, lim, carryin, RehH, RehL);

  // ---- y = Re(h)@C^T + in@D^T ----
  seg_clear(sd);
  NT  = seg_add3(sd, 0, RehH, RehL, CH_, CL_, SS);
  NT += seg_add3(sd, 3, inH,  inL,  DH_, DL_, UU);
  gemm8<<<(BT/256)*(OO/128), 512, 0, stream>>>(sd, NT, yH, yL, nullptr, OO, 1, OO/128);

  if (full){
    unsigned short* z1H = (unsigned short*)R1;                 // 64 MB
    unsigned short* z1L = (unsigned short*)R2;                 // 64 MB (contiguous after R1)
    unsigned short* z2H = (unsigned short*)z2reg;
    unsigned short* z2L = (unsigned short*)(z2reg + (size_t)BT*HH*2);

    seg_clear(sd); NT = seg_add3(sd, 0, yH, yL, W1H, W1L, OO);
    gemm8<<<(BT/256)*(HH/128), 512, 0, stream>>>(sd, NT, z1H, z1L, nullptr, HH, 2, HH/128);

    seg_clear(sd); NT = seg_add3(sd, 0, z1H, z1L, W2H, W2L, HH);
    gemm8<<<(BT/256)*(HH/128), 512, 0, stream>>>(sd, NT, z2H, z2L, nullptr, HH, 3, HH/128);

    seg_clear(sd);
    NT  = seg_add3(sd, 0, z2H, z2L, W3H, W3L, HH);
    NT += seg_add3(sd, 3, inH, inL, WlH, WlL, UU);
    gemm8<<<(BT/256)*(OO/128), 512, 0, stream>>>(sd, NT, nullptr, nullptr, out, OO, 0, OO/128);
  } else {
    unsigned short* z1H = (unsigned short*)R1;
    unsigned short* z1L = (unsigned short*)(R1 + (size_t)(BT/2)*HH*2);
    unsigned short* z2H = (unsigned short*)R2;
    unsigned short* z2L = (unsigned short*)(R2 + (size_t)(BT/2)*HH*2);
    for (int c = 0; c < 2; c++){
      const size_t ro = (size_t)c * (BT/2);
      seg_clear(sd); NT = seg_add3(sd, 0, yH + ro*OO, yL + ro*OO, W1H, W1L, OO);
      gemm8<<<(BT/2/256)*(HH/128), 512, 0, stream>>>(sd, NT, z1H, z1L, nullptr, HH, 2, HH/128);

      seg_clear(sd); NT = seg_add3(sd, 0, z1H, z1L, W2H, W2L, HH);
      gemm8<<<(BT/2/256)*(HH/128), 512, 0, stream>>>(sd, NT, z2H, z2L, nullptr, HH, 3, HH/128);

      seg_clear(sd);
      NT  = seg_add3(sd, 0, z2H, z2L, W3H, W3L, HH);
      NT += seg_add3(sd, 3, inH + ro*UU, inL + ro*UU, WlH, WlL, UU);
      gemm8<<<(BT/2/256)*(OO/128), 512, 0, stream>>>(sd, NT, nullptr, nullptr, out + ro*OO, OO, 0, OO/128);
    }
  }
}

// Round 5
// 376.808 us; speedup vs baseline: 1.4422x; 1.4422x over previous
//
#include <hip/hip_runtime.h>
#include <hip/hip_bf16.h>

#define BSZ 16
#define TT 4096
#define UU 128
#define OO 128
#define SS 256
#define HH 512
#define BT (BSZ*TT)      // 65536 rows
#define CLEN 64          // scan chunk length
#define NCH (TT/CLEN)    // 64 chunks per sequence

using bf16x8 = __attribute__((ext_vector_type(8))) short;
using f32x4  = __attribute__((ext_vector_type(4))) float;

__device__ __forceinline__ unsigned short f2bf(float x){
  union { float f; unsigned int u; } v; v.f = x;
  unsigned int r = v.u + 0x7fffu + ((v.u >> 16) & 1u);
  return (unsigned short)(r >> 16);
}
__device__ __forceinline__ float bf2f(unsigned short h){
  union { float f; unsigned int u; } v; v.u = ((unsigned int)h) << 16;
  return v.f;
}

// async global->LDS, 16B per lane (linear dest; source carries the swizzle)
#define GLD16(g, s) __builtin_amdgcn_global_load_lds( \
    (const __attribute__((address_space(1))) unsigned int*)(g), \
    (__attribute__((address_space(3))) unsigned int*)(s), 16, 0, 0)

#define PHASE_BAR() do{ __builtin_amdgcn_sched_barrier(0); \
                        __builtin_amdgcn_s_barrier(); \
                        __builtin_amdgcn_sched_barrier(0); }while(0)

// ---------------- split fp32 -> (hi, lo) bf16 planes ----------------
__global__ __launch_bounds__(256) void split_k(const float* __restrict__ x,
                                               unsigned short* __restrict__ H,
                                               unsigned short* __restrict__ L, int n4){
  int i = blockIdx.x * 256 + threadIdx.x;
  if (i >= n4) return;
  float4 v = ((const float4*)x)[i];
  unsigned short h0 = f2bf(v.x), h1 = f2bf(v.y), h2 = f2bf(v.z), h3 = f2bf(v.w);
  ushort4 hh = make_ushort4(h0, h1, h2, h3);
  ushort4 ll = make_ushort4(f2bf(v.x - bf2f(h0)), f2bf(v.y - bf2f(h1)),
                            f2bf(v.z - bf2f(h2)), f2bf(v.w - bf2f(h3)));
  ((ushort4*)H)[i] = hh;
  ((ushort4*)L)[i] = ll;
}

struct SegDesc {
  const unsigned short* a[6];
  const unsigned short* b[6];
  int tiles[6];    // K-tiles (of 64) per segment; 0 = unused
  int stride[6];   // row stride (elements) of that segment's sources
};

// =================== gemm256: m201-style 4-phase 256x256 ===================
// BM=BN=256, BK=64, 512 threads = 8 waves (2M x 4N), per-wave 128x64 out.
// LDS: 4 half-slots x 32KB (A[128][64] + B[128][64] each) = 128 KB ring.
// Per tile: 4 phases, each { stage 1 unit | ds_read frags | bar | MFMA16 | bar },
// one counted vmcnt(4) per tile (phase 0), setprio around MFMA, XOR-swizzle.
__global__ __launch_bounds__(512, 1) void gemm256(SegDesc sd, int NT,
    unsigned short* __restrict__ outH, unsigned short* __restrict__ outL,
    float* __restrict__ outF, int Nout, int EPI, int gx)
{
  __shared__ __align__(16) unsigned short LDS[4*16384];   // 128 KB

  const int tid = threadIdx.x;
  const int l = tid & 63, w = tid >> 6;
  const int wr = w >> 2, wc = w & 3;        // 2M x 4N wave grid
  const int fr = l & 15, fq = l >> 4;

  // XCD-chunked bijective-ish swizzle (all grids here are %8==0)
  const int nwg = gridDim.x;
  const int bid = blockIdx.x;
  const int q8 = nwg >> 3;
  const int swz = (bid & 7) * q8 + (bid >> 3);
  const int nb = swz % gx;
  const int mb = swz / gx;

  auto stage_unit = [&](int t, int h, int isB){
    const unsigned short* p = sd.a[0]; int st = sd.stride[0], kb = 0, cum = 0;
    #pragma unroll
    for (int s = 0; s < 6; s++){
      int tl = sd.tiles[s];
      if (t >= cum && t < cum + tl){ p = isB ? sd.b[s] : sd.a[s]; st = sd.stride[s]; kb = cum; }
      cum += tl;
    }
    const int kk = (t - kb) << 6;
    const int row0 = (isB ? nb : mb) * 256 + h * 128;
    unsigned short* dst = &LDS[((2*t + h) & 3) * 16384 + (isB ? 8192 : 0)];
    #pragma unroll
    for (int j = 0; j < 2; j++){
      int seg = tid + (j << 9);
      int r = seg >> 3, c = seg & 7;
      int sc = (c ^ (r & 7)) << 3;
      GLD16(p + (size_t)(row0 + r) * st + kk + sc, dst + seg * 8);
    }
  };

  f32x4 acc[8][4];
  #pragma unroll
  for (int m = 0; m < 8; m++)
    #pragma unroll
    for (int n = 0; n < 4; n++) acc[m][n] = f32x4{0.f, 0.f, 0.f, 0.f};

  // prologue: A0(0), A1(0), B0(0), B1(0), A0(1)  (10 loads/thread)
  stage_unit(0, 0, 0); stage_unit(0, 1, 0);
  stage_unit(0, 0, 1); stage_unit(0, 1, 1);
  if (1 < NT) stage_unit(1, 0, 0);

  bf16x8 Bfr[4];
  auto phase_mfma = [&](int aslot, int bslot, int mh, int ks, bool loadB){
    if (loadB){
      #pragma unroll
      for (int n = 0; n < 4; n++){
        int lr = (wc & 1) * 64 + n * 16 + fr;
        Bfr[n] = *(const bf16x8*)&LDS[bslot + lr*64 + (((ks*4 + fq) ^ (lr & 7)) << 3)];
      }
    }
    bf16x8 Afr[4];
    #pragma unroll
    for (int m = 0; m < 4; m++){
      int lr = mh * 64 + m * 16 + fr;
      Afr[m] = *(const bf16x8*)&LDS[aslot + lr*64 + (((ks*4 + fq) ^ (lr & 7)) << 3)];
    }
    __builtin_amdgcn_s_setprio(1);
    #pragma unroll
    for (int m = 0; m < 4; m++)
      #pragma unroll
      for (int n = 0; n < 4; n++)
        acc[mh*4 + m][n] = __builtin_amdgcn_mfma_f32_16x16x32_bf16(Afr[m], Bfr[n], acc[mh*4 + m][n], 0, 0, 0);
    __builtin_amdgcn_s_setprio(0);
  };

  for (int t = 0; t < NT; t++){
    const int aslot = ((2*t + wr) & 3) * 16384;
    const int bslot = ((2*t + (wc >> 1)) & 3) * 16384 + 8192;
    // ---- P0: stage A1(t+1); counted vmcnt; quadrant (mh0, ks0) ----
    if (t + 1 < NT){
      stage_unit(t + 1, 1, 0);
      asm volatile("s_waitcnt vmcnt(4)" ::: "memory");
    } else {
      asm volatile("s_waitcnt vmcnt(0)" ::: "memory");
    }
    PHASE_BAR();
    phase_mfma(aslot, bslot, 0, 0, true);
    PHASE_BAR();
    // ---- P1: stage B0(t+1); quadrant (mh1, ks0) ----
    if (t + 1 < NT) stage_unit(t + 1, 0, 1);
    phase_mfma(aslot, bslot, 1, 0, false);
    PHASE_BAR();
    // ---- P2: stage B1(t+1); quadrant (mh0, ks1) ----
    if (t + 1 < NT) stage_unit(t + 1, 1, 1);
    phase_mfma(aslot, bslot, 0, 1, true);
    PHASE_BAR();
    // ---- P3: stage A0(t+2); quadrant (mh1, ks1) ----
    if (t + 2 < NT) stage_unit(t + 2, 0, 0);
    phase_mfma(aslot, bslot, 1, 1, false);
    PHASE_BAR();
  }

  #pragma unroll
  for (int mf = 0; mf < 8; mf++){
    int rowb = mb*256 + wr*128 + mf*16 + fq*4;
    #pragma unroll
    for (int n = 0; n < 4; n++){
      int col = nb*256 + wc*64 + n*16 + fr;
      #pragma unroll
      for (int j = 0; j < 4; j++){
        float x = acc[mf][n][j];
        size_t o = (size_t)(rowb + j) * Nout + col;
        if (EPI == 0){
          outF[o] = x;
        } else {
          if (EPI == 2)      x = x / (1.f + __expf(-x));   // silu
          else if (EPI == 3) x = fmaxf(x, 0.f);            // relu
          unsigned short h = f2bf(x);
          outH[o] = h;
          outL[o] = f2bf(x - bf2f(h));
        }
      }
    }
  }
}

// =================== gemm_split: 128x128 2-phase (N=128 ops) ===================
// 3-term split: ah*bh + al*bh + ah*bl, fp32 acc. BK=32, double-buffered LDS,
// XOR-swizzled (source-side) to kill the residual bank conflicts.
__global__ __launch_bounds__(256, 2) void gemm_split(
    const unsigned short* __restrict__ AH1, const unsigned short* __restrict__ AL1,
    const unsigned short* __restrict__ BH1, const unsigned short* __restrict__ BL1, int K1,
    const unsigned short* __restrict__ AH2, const unsigned short* __restrict__ AL2,
    const unsigned short* __restrict__ BH2, const unsigned short* __restrict__ BL2, int K2,
    unsigned short* __restrict__ outH, unsigned short* __restrict__ outL,
    float* __restrict__ outF, int Nout, int EPI)
{
  __shared__ __align__(16) unsigned short Ah[2][128*32];
  __shared__ __align__(16) unsigned short Al[2][128*32];
  __shared__ __align__(16) unsigned short Bh[2][128*32];
  __shared__ __align__(16) unsigned short Bl[2][128*32];
  const int tid = threadIdx.x;
  const int mb = blockIdx.x, nb = blockIdx.y;
  const int l = tid & 63, w = tid >> 6;
  const int wr = w >> 1, wc = w & 1;
  const int fr = l & 15, fq = l >> 4;

  f32x4 acc[4][4];
  #pragma unroll
  for (int m = 0; m < 4; m++)
    #pragma unroll
    for (int n = 0; n < 4; n++) acc[m][n] = f32x4{0.f, 0.f, 0.f, 0.f};

  const int nkt = (K1 + K2) >> 5;

  auto STAGE = [&](int buf, int kt){
    const int k0 = kt << 5;
    const unsigned short *aH, *aL, *bH, *bL; int st, kk;
    if (k0 < K1){ aH = AH1; aL = AL1; bH = BH1; bL = BL1; st = K1; kk = k0; }
    else        { aH = AH2; aL = AL2; bH = BH2; bL = BL2; st = K2; kk = k0 - K1; }
    #pragma unroll
    for (int it = 0; it < 2; it++){
      int seg = tid + it * 256;
      int r = seg >> 2, c4 = seg & 3;
      int sc = (c4 ^ (r & 3)) << 3;
      size_t go = (size_t)(mb*128 + r) * st + kk + sc;
      size_t gb = (size_t)(nb*128 + r) * st + kk + sc;
      int lo = r*32 + c4*8;
      GLD16(aH + go, &Ah[buf][lo]);
      GLD16(aL + go, &Al[buf][lo]);
      GLD16(bH + gb, &Bh[buf][lo]);
      GLD16(bL + gb, &Bl[buf][lo]);
    }
  };

  STAGE(0, 0);
  __syncthreads();

  for (int kt = 0; kt < nkt; kt++){
    const int cur = kt & 1;
    if (kt + 1 < nkt) STAGE(cur ^ 1, kt + 1);

    bf16x8 a_h[4], a_l[4], b_h[4], b_l[4];
    #pragma unroll
    for (int m = 0; m < 4; m++){
      int lra = wr*64 + m*16 + fr;
      int ra = lra*32 + ((fq ^ (lra & 3)) << 3);
      a_h[m] = *(const bf16x8*)&Ah[cur][ra];
      a_l[m] = *(const bf16x8*)&Al[cur][ra];
      int lrb = wc*64 + m*16 + fr;
      int rb = lrb*32 + ((fq ^ (lrb & 3)) << 3);
      b_h[m] = *(const bf16x8*)&Bh[cur][rb];
      b_l[m] = *(const bf16x8*)&Bl[cur][rb];
    }
    __builtin_amdgcn_s_setprio(1);
    #pragma unroll
    for (int m = 0; m < 4; m++)
      #pragma unroll
      for (int n = 0; n < 4; n++)
        acc[m][n] = __builtin_amdgcn_mfma_f32_16x16x32_bf16(a_h[m], b_h[n], acc[m][n], 0, 0, 0);
    #pragma unroll
    for (int m = 0; m < 4; m++)
      #pragma unroll
      for (int n = 0; n < 4; n++)
        acc[m][n] = __builtin_amdgcn_mfma_f32_16x16x32_bf16(a_l[m], b_h[n], acc[m][n], 0, 0, 0);
    #pragma unroll
    for (int m = 0; m < 4; m++)
      #pragma unroll
      for (int n = 0; n < 4; n++)
        acc[m][n] = __builtin_amdgcn_mfma_f32_16x16x32_bf16(a_h[m], b_l[n], acc[m][n], 0, 0, 0);
    __builtin_amdgcn_s_setprio(0);

    __syncthreads();
  }

  #pragma unroll
  for (int m = 0; m < 4; m++){
    int rowb = mb*128 + wr*64 + m*16 + fq*4;
    #pragma unroll
    for (int n = 0; n < 4; n++){
      int col = nb*128 + wc*64 + n*16 + fr;
      #pragma unroll
      for (int j = 0; j < 4; j++){
        float x = acc[m][n][j];
        size_t o = (size_t)(rowb + j) * Nout + col;
        if (EPI == 0){
          outF[o] = x;
        } else {
          if (EPI == 2)      x = x / (1.f + __expf(-x));
          else if (EPI == 3) x = fmaxf(x, 0.f);
          unsigned short h = f2bf(x);
          outH[o] = h;
          outL[o] = f2bf(x - bf2f(h));
        }
      }
    }
  }
}

// ---------------- scan kernels ----------------
__global__ __launch_bounds__(256) void scan_ends(const float* __restrict__ bu,
                                                 const float* __restrict__ lre,
                                                 const float* __restrict__ lim,
                                                 float2* __restrict__ ends){
  const int s = threadIdx.x;
  const int b = blockIdx.x >> 6;
  const int c = blockIdx.x & 63;
  const float lr = lre[s], li = lim[s];
  float hr = 0.f, hi = 0.f;
  const float* p = bu + ((size_t)b*TT + (size_t)c*CLEN)*SS + s;
  #pragma unroll 8
  for (int t = 0; t < CLEN; t++){
    float x  = p[(size_t)t * SS];
    float nr = fmaf(lr, hr, fmaf(-li, hi, x));
    float ni = fmaf(lr, hi, li * hr);
    hr = nr; hi = ni;
  }
  ends[((size_t)b*NCH + c)*SS + s] = make_float2(hr, hi);
}

__global__ __launch_bounds__(256) void scan_carries(const float2* __restrict__ ends,
                                                    const float* __restrict__ lre,
                                                    const float* __restrict__ lim,
                                                    float2* __restrict__ carryin){
  const int idx = blockIdx.x * 256 + threadIdx.x;
  const int b = idx >> 8;
  const int s = idx & 255;
  float pr = lre[s], pi = lim[s];
  #pragma unroll
  for (int q = 0; q < 6; q++){
    float nr = pr*pr - pi*pi;
    float ni = 2.f * pr * pi;
    pr = nr; pi = ni;
  }
  float hr = 0.f, hi = 0.f;
  for (int c = 0; c < NCH; c++){
    size_t o = ((size_t)b*NCH + c)*SS + s;
    carryin[o] = make_float2(hr, hi);
    float2 e = ends[o];
    float nr = fmaf(pr, hr, fmaf(-pi, hi, e.x));
    float ni = fmaf(pr, hi, fmaf(pi, hr, e.y));
    hr = nr; hi = ni;
  }
}

__global__ __launch_bounds__(256) void scan_apply(const float* __restrict__ bu,
                                                  const float* __restrict__ lre,
                                                  const float* __restrict__ lim,
                                                  const float2* __restrict__ carryin,
                                                  unsigned short* __restrict__ RehH,
                                                  unsigned short* __restrict__ RehL){
  const int s = threadIdx.x;
  const int b = blockIdx.x >> 6;
  const int c = blockIdx.x & 63;
  const float lr = lre[s], li = lim[s];
  float2 h0 = carryin[((size_t)b*NCH + c)*SS + s];
  float hr = h0.x, hi = h0.y;
  const size_t base = ((size_t)b*TT + (size_t)c*CLEN)*SS + s;
  #pragma unroll 4
  for (int t = 0; t < CLEN; t++){
    float x  = bu[base + (size_t)t * SS];
    float nr = fmaf(lr, hr, fmaf(-li, hi, x));
    float ni = fmaf(lr, hi, li * hr);
    hr = nr; hi = ni;
    unsigned short h = f2bf(hr);
    RehH[base + (size_t)t * SS] = h;
    RehL[base + (size_t)t * SS] = f2bf(hr - bf2f(h));
  }
}

// ---------------- host-side segment builders ----------------
static void seg_clear(SegDesc& sd){
  for (int i = 0; i < 6; i++){ sd.a[i]=nullptr; sd.b[i]=nullptr; sd.tiles[i]=0; sd.stride[i]=0; }
}
static int seg_add3(SegDesc& sd, int at,
                    const unsigned short* aH, const unsigned short* aL,
                    const unsigned short* bH, const unsigned short* bL, int K){
  int t = K >> 6;
  sd.a[at+0]=aH; sd.b[at+0]=bH; sd.tiles[at+0]=t; sd.stride[at+0]=K;
  sd.a[at+1]=aL; sd.b[at+1]=bH; sd.tiles[at+1]=t; sd.stride[at+1]=K;
  sd.a[at+2]=aH; sd.b[at+2]=bL; sd.tiles[at+2]=t; sd.stride[at+2]=K;
  return 3*t;
}
static int seg_add2(SegDesc& sd, int at,
                    const unsigned short* aH, const unsigned short* aL,
                    const unsigned short* bH, int K){
  int t = K >> 6;
  sd.a[at+0]=aH; sd.b[at+0]=bH; sd.tiles[at+0]=t; sd.stride[at+0]=K;
  sd.a[at+1]=aL; sd.b[at+1]=bH; sd.tiles[at+1]=t; sd.stride[at+1]=K;
  return 2*t;
}

extern "C" void kernel_launch(void* const* d_in, const int* in_sizes, int n_in,
                              void* d_out, int out_size, void* d_ws, size_t ws_size,
                              hipStream_t stream){
  const float* inp = (const float*)d_in[0];
  const float* lre = (const float*)d_in[1];
  const float* lim = (const float*)d_in[2];
  const float* Bm  = (const float*)d_in[3];
  const float* Cm  = (const float*)d_in[4];
  const float* Dm  = (const float*)d_in[5];
  const float* W1  = (const float*)d_in[6];
  const float* W2  = (const float*)d_in[7];
  const float* W3  = (const float*)d_in[8];
  const float* Wl  = (const float*)d_in[9];
  float* out = (float*)d_out;

  char* ws = (char*)d_ws;
  size_t off = 0;
  auto alloc = [&](size_t bytes)->char*{
    char* p = ws + off; off += (bytes + 255) & ~(size_t)255; return p;
  };
  unsigned short* inH = (unsigned short*)alloc((size_t)BT*UU*2);
  unsigned short* inL = (unsigned short*)alloc((size_t)BT*UU*2);
  unsigned short* BwH = (unsigned short*)alloc((size_t)SS*UU*2);
  unsigned short* BwL = (unsigned short*)alloc((size_t)SS*UU*2);
  unsigned short* CH_ = (unsigned short*)alloc((size_t)OO*SS*2);
  unsigned short* CL_ = (unsigned short*)alloc((size_t)OO*SS*2);
  unsigned short* DH_ = (unsigned short*)alloc((size_t)OO*UU*2);
  unsigned short* DL_ = (unsigned short*)alloc((size_t)OO*UU*2);
  unsigned short* W1H = (unsigned short*)alloc((size_t)HH*OO*2);
  unsigned short* W1L = (unsigned short*)alloc((size_t)HH*OO*2);
  unsigned short* W2H = (unsigned short*)alloc((size_t)HH*HH*2);
  unsigned short* W2L = (unsigned short*)alloc((size_t)HH*HH*2);
  unsigned short* W3H = (unsigned short*)alloc((size_t)OO*HH*2);
  unsigned short* W3L = (unsigned short*)alloc((size_t)OO*HH*2);
  unsigned short* WlH = (unsigned short*)alloc((size_t)OO*UU*2);
  unsigned short* WlL = (unsigned short*)alloc((size_t)OO*UU*2);
  float2* ends    = (float2*)alloc((size_t)BSZ*NCH*SS*8);
  float2* carryin = (float2*)alloc((size_t)BSZ*NCH*SS*8);
  char* R1 = alloc((size_t)BT*SS*4);     // 64 MB: bu -> z1 space
  char* R2 = alloc((size_t)BT*SS*4);     // 64 MB: Reh planes -> z1/z2 space
  unsigned short* yH = (unsigned short*)alloc((size_t)BT*OO*2);
  unsigned short* yL = (unsigned short*)alloc((size_t)BT*OO*2);
  if (off > ws_size) return;

  float* bu = (float*)R1;
  unsigned short* RehH = (unsigned short*)R2;
  unsigned short* RehL = (unsigned short*)(R2 + (size_t)BT*SS*2);

  bool full = false;
  char* z2reg = nullptr;
  {
    size_t need = off + (size_t)BT*HH*2*2;
    if (need <= ws_size){ z2reg = alloc((size_t)BT*HH*2*2); full = true; }
  }

  // ---- split input + weights into bf16 hi/lo planes ----
  split_k<<<(BT*UU/4 + 255)/256, 256, 0, stream>>>(inp, inH, inL, BT*UU/4);
  split_k<<<(SS*UU/4 + 255)/256, 256, 0, stream>>>(Bm, BwH, BwL, SS*UU/4);
  split_k<<<(OO*SS/4 + 255)/256, 256, 0, stream>>>(Cm, CH_, CL_, OO*SS/4);
  split_k<<<(OO*UU/4 + 255)/256, 256, 0, stream>>>(Dm, DH_, DL_, OO*UU/4);
  split_k<<<(HH*OO/4 + 255)/256, 256, 0, stream>>>(W1, W1H, W1L, HH*OO/4);
  split_k<<<(HH*HH/4 + 255)/256, 256, 0, stream>>>(W2, W2H, W2L, HH*HH/4);
  split_k<<<(OO*HH/4 + 255)/256, 256, 0, stream>>>(W3, W3H, W3L, OO*HH/4);
  split_k<<<(OO*UU/4 + 255)/256, 256, 0, stream>>>(Wl, WlH, WlL, OO*UU/4);

  SegDesc sd; int NT;

  // ---- bu = input @ B^T (3-term, gemm256, fp32 out for the scan) ----
  seg_clear(sd); NT = seg_add3(sd, 0, inH, inL, BwH, BwL, UU);   // NT=6
  gemm256<<<(BT/256)*(SS/256), 512, 0, stream>>>(sd, NT, nullptr, nullptr, bu, SS, 0, SS/256);

  // ---- diagonal complex scan ----
  scan_ends<<<BSZ*NCH, 256, 0, stream>>>(bu, lre, lim, ends);
  scan_carries<<<(BSZ*SS)/256, 256, 0, stream>>>(ends, lre, lim, carryin);
  scan_apply<<<BSZ*NCH, 256, 0, stream>>>(bu, lre, lim, carryin, RehH, RehL);

  // ---- y = Re(h)@C^T + in@D^T (3-term, gemm_split 128x128) ----
  gemm_split<<<dim3(BT/128, OO/128), 256, 0, stream>>>(
      RehH, RehL, CH_, CL_, SS,  inH, inL, DH_, DL_, UU,
      yH, yL, nullptr, OO, 1);

  if (full){
    unsigned short* z1H = (unsigned short*)R1;
    unsigned short* z1L = (unsigned short*)R2;
    unsigned short* z2H = (unsigned short*)z2reg;
    unsigned short* z2L = (unsigned short*)(z2reg + (size_t)BT*HH*2);

    // z1 = silu(y @ W1^T): 2-term, gemm256, K=128 -> NT=4
    seg_clear(sd); NT = seg_add2(sd, 0, yH, yL, W1H, OO);
    gemm256<<<(BT/256)*(HH/256), 512, 0, stream>>>(sd, NT, z1H, z1L, nullptr, HH, 2, HH/256);

    // z2 = relu(z1 @ W2^T): 2-term, gemm256, K=512 -> NT=16
    seg_clear(sd); NT = seg_add2(sd, 0, z1H, z1L, W2H, HH);
    gemm256<<<(BT/256)*(HH/256), 512, 0, stream>>>(sd, NT, z2H, z2L, nullptr, HH, 3, HH/256);

    // out = z2 @ W3^T + in @ Wlin^T (3-term, gemm_split)
    gemm_split<<<dim3(BT/128, OO/128), 256, 0, stream>>>(
        z2H, z2L, W3H, W3L, HH,
        inH, inL, WlH, WlL, UU,
        nullptr, nullptr, out, OO, 0);
  } else {
    unsigned short* z1H = (unsigned short*)R1;
    unsigned short* z1L = (unsigned short*)(R1 + (size_t)(BT/2)*HH*2);
    unsigned short* z2H = (unsigned short*)R2;
    unsigned short* z2L = (unsigned short*)(R2 + (size_t)(BT/2)*HH*2);
    for (int c = 0; c < 2; c++){
      const size_t ro = (size_t)c * (BT/2);
      seg_clear(sd); NT = seg_add2(sd, 0, yH + ro*OO, yL + ro*OO, W1H, OO);
      gemm256<<<(BT/2/256)*(HH/256), 512, 0, stream>>>(sd, NT, z1H, z1L, nullptr, HH, 2, HH/256);

      seg_clear(sd); NT = seg_add2(sd, 0, z1H, z1L, W2H, HH);
      gemm256<<<(BT/2/256)*(HH/256), 512, 0, stream>>>(sd, NT, z2H, z2L, nullptr, HH, 3, HH/256);

      gemm_split<<<dim3(BT/2/128, OO/128), 256, 0, stream>>>(
          z2H, z2L, W3H, W3L, HH,
          inH + ro*UU, inL + ro*UU, WlH, WlL, UU,
          nullptr, nullptr, out + ro*OO, OO, 0);
    }
  }
}

// Round 6
// 302.171 us; speedup vs baseline: 1.7984x; 1.2470x over previous
//
#include <hip/hip_runtime.h>
#include <hip/hip_bf16.h>

#define BSZ 16
#define TT 4096
#define UU 128
#define OO 128
#define SS 256
#define HH 512
#define BT (BSZ*TT)      // 65536 rows
#define CLEN 64          // scan chunk length
#define NCH (TT/CLEN)    // 64 chunks per sequence

using bf16x8 = __attribute__((ext_vector_type(8))) short;
using f32x4  = __attribute__((ext_vector_type(4))) float;

__device__ __forceinline__ unsigned short f2bf(float x){
  union { float f; unsigned int u; } v; v.f = x;
  unsigned int r = v.u + 0x7fffu + ((v.u >> 16) & 1u);
  return (unsigned short)(r >> 16);
}
__device__ __forceinline__ float bf2f(unsigned short h){
  union { float f; unsigned int u; } v; v.u = ((unsigned int)h) << 16;
  return v.f;
}

// async global->LDS, 16B per lane (linear dest; source carries the swizzle)
#define GLD16(g, s) __builtin_amdgcn_global_load_lds( \
    (const __attribute__((address_space(1))) unsigned int*)(g), \
    (__attribute__((address_space(3))) unsigned int*)(s), 16, 0, 0)

#define SBAR() do{ __builtin_amdgcn_sched_barrier(0); \
                   __builtin_amdgcn_s_barrier(); \
                   __builtin_amdgcn_sched_barrier(0); }while(0)

// ---------------- split fp32 -> (hi, lo) bf16 planes ----------------
__global__ __launch_bounds__(256) void split_k(const float* __restrict__ x,
                                               unsigned short* __restrict__ H,
                                               unsigned short* __restrict__ L, int n4){
  int i = blockIdx.x * 256 + threadIdx.x;
  if (i >= n4) return;
  float4 v = ((const float4*)x)[i];
  unsigned short h0 = f2bf(v.x), h1 = f2bf(v.y), h2 = f2bf(v.z), h3 = f2bf(v.w);
  ushort4 hh = make_ushort4(h0, h1, h2, h3);
  ushort4 ll = make_ushort4(f2bf(v.x - bf2f(h0)), f2bf(v.y - bf2f(h1)),
                            f2bf(v.z - bf2f(h2)), f2bf(v.w - bf2f(h3)));
  ((ushort4*)H)[i] = hh;
  ((ushort4*)L)[i] = ll;
}

struct SegDesc {
  const unsigned short* a[6];
  const unsigned short* b[6];
  int tiles[6];    // K-tiles (of 64) per segment; 0 = unused
  int stride[6];   // row stride (elements) of that segment's sources
};

// =================== gemm256: derived 8-phase 256x256 ===================
// BM=BN=256, BK=64, 512 thr = 8 waves (2M x 4N), per-wave 128x64 out.
// Units = {A,B} x {k-half 0,1} per K-tile (16 KB each; 2 GLD16/thread).
// LDS: 4 A-slots + 4 B-slots x 16 KB = 128 KB. Unit u staged at phase u-6
// (slot freed at end of phase u-7 -> barrier-ordered, race-free).
// vmcnt(4) once per tile (q==3): last 2 issued units may stay in flight.
// Phase: {ds_read frags | stage unit | [vmcnt] | bar | MFMA x16 | bar}.
__global__ __launch_bounds__(512, 1) void gemm256(SegDesc sd, int NT,
    unsigned short* __restrict__ outH, unsigned short* __restrict__ outL,
    float* __restrict__ outF, int Nout, int EPI, int gx)
{
  __shared__ __align__(16) unsigned short LDS[65536];   // 128 KB

  const int tid = threadIdx.x;
  const int l = tid & 63, w = tid >> 6;
  const int wr = w >> 2, wc = w & 3;        // 2M x 4N wave grid
  const int fr = l & 15, fq = l >> 4;

  const int nwg = gridDim.x, bid = blockIdx.x;
  const int q8 = nwg >> 3;
  const int swz = (bid & 7) * q8 + (bid >> 3);
  const int nb = swz % gx, mb = swz / gx;

  const int total_u = 4 * NT;

  auto stage_unit = [&](int u){
    const int Tu = u >> 2, ksu = (u >> 1) & 1, isB = u & 1;
    const unsigned short* p = sd.a[0]; int st = sd.stride[0], kb = 0, cum = 0;
    #pragma unroll
    for (int s = 0; s < 6; s++){
      int tl = sd.tiles[s];
      if (tl && Tu >= cum && Tu < cum + tl){ p = isB ? sd.b[s] : sd.a[s]; st = sd.stride[s]; kb = cum; }
      cum += tl;
    }
    const int kk = ((Tu - kb) << 6) + (ksu << 5);
    const int row0 = (isB ? nb : mb) << 8;
    unsigned short* dst = &LDS[(isB ? 32768 : 0) + (((u >> 1) & 3) << 13)];
    #pragma unroll
    for (int j = 0; j < 2; j++){
      int seg = tid + (j << 9);               // 1024 segs of 16B (256 rows x 4)
      int r = seg >> 2, c4 = seg & 3;
      int sc = (c4 ^ ((r >> 1) & 3)) << 3;    // inverse swizzle at source
      GLD16(p + (size_t)(row0 + r) * st + kk + sc, dst + seg * 8);
    }
  };

  f32x4 acc[8][4];
  #pragma unroll
  for (int m = 0; m < 8; m++)
    #pragma unroll
    for (int n = 0; n < 4; n++) acc[m][n] = f32x4{0.f, 0.f, 0.f, 0.f};

  // prologue: units 0..5 (tile0 complete + tile1 k0), then drain to tile0-ready
  for (int u = 0; u < 6 && u < total_u; u++) stage_unit(u);
  if (total_u > 6) asm volatile("s_waitcnt vmcnt(4)" ::: "memory");
  else             asm volatile("s_waitcnt vmcnt(0)" ::: "memory");
  SBAR();

  bf16x8 Bfr[4];
  for (int T = 0; T < NT; T++){
    #pragma unroll
    for (int q = 0; q < 4; q++){
      const int mh = q & 1, ks = q >> 1;
      const int abase = (((2*T + ks) & 3) << 13);
      const int bbase = 32768 + abase;
      // ds_read fragments for THIS phase (data guaranteed by prev tile's vmcnt)
      bf16x8 Afr[4];
      #pragma unroll
      for (int m = 0; m < 4; m++){
        int row = wr*128 + mh*64 + m*16 + fr;
        Afr[m] = *(const bf16x8*)&LDS[abase + row*32 + ((fq ^ ((row>>1)&3)) << 3)];
      }
      if (mh == 0){
        #pragma unroll
        for (int n = 0; n < 4; n++){
          int row = wc*64 + n*16 + fr;
          Bfr[n] = *(const bf16x8*)&LDS[bbase + row*32 + ((fq ^ ((row>>1)&3)) << 3)];
        }
      }
      // stage one unit, 6 phases ahead
      int u = 4*T + q + 6;
      if (u < total_u) stage_unit(u);
      if (q == 3){
        if (T < NT-2)       asm volatile("s_waitcnt vmcnt(4)" ::: "memory");
        else if (T == NT-2) asm volatile("s_waitcnt vmcnt(0)" ::: "memory");
      }
      SBAR();
      __builtin_amdgcn_s_setprio(1);
      #pragma unroll
      for (int m = 0; m < 4; m++)
        #pragma unroll
        for (int n = 0; n < 4; n++)
          acc[mh*4+m][n] = __builtin_amdgcn_mfma_f32_16x16x32_bf16(Afr[m], Bfr[n], acc[mh*4+m][n], 0, 0, 0);
      __builtin_amdgcn_s_setprio(0);
      SBAR();
    }
  }

  // ---- coalesced epilogue: acc -> LDS f32 (128x256 half) -> 16B stores ----
  float* fl = (float*)LDS;
  #pragma unroll
  for (int h = 0; h < 2; h++){
    if (wr == h){
      #pragma unroll
      for (int mf = 0; mf < 8; mf++)
        #pragma unroll
        for (int n = 0; n < 4; n++)
          #pragma unroll
          for (int j = 0; j < 4; j++)
            fl[(mf*16 + fq*4 + j)*256 + wc*64 + n*16 + fr] = acc[mf][n][j];
    }
    __syncthreads();
    #pragma unroll
    for (int it = 0; it < 8; it++){
      int task = tid + (it << 9);
      int rl = task >> 5, cg = task & 31;
      float4 v0 = *(const float4*)&fl[rl*256 + cg*8];
      float4 v1 = *(const float4*)&fl[rl*256 + cg*8 + 4];
      size_t o = (size_t)(mb*256 + h*128 + rl) * Nout + nb*256 + cg*8;
      if (EPI == 0){
        *(float4*)(outF + o)     = v0;
        *(float4*)(outF + o + 4) = v1;
      } else {
        float xv[8] = {v0.x,v0.y,v0.z,v0.w,v1.x,v1.y,v1.z,v1.w};
        union { unsigned short us[8]; uint4 v; } ph, pl;
        #pragma unroll
        for (int e = 0; e < 8; e++){
          float x = xv[e];
          if (EPI == 2)      x = x / (1.f + __expf(-x));   // silu
          else if (EPI == 3) x = fmaxf(x, 0.f);            // relu
          ph.us[e] = f2bf(x);
          pl.us[e] = f2bf(x - bf2f(ph.us[e]));
        }
        *(uint4*)(outH + o) = ph.v;
        if (outL) *(uint4*)(outL + o) = pl.v;
      }
    }
    __syncthreads();
  }
}

// =================== gemm_split: 128x128 2-phase (N=128 ops) ===================
// Terms per source via flags: bit0 = al*bh, bit1 = ah*bl (ah*bh always).
__global__ __launch_bounds__(256, 2) void gemm_split(
    const unsigned short* __restrict__ AH1, const unsigned short* __restrict__ AL1,
    const unsigned short* __restrict__ BH1, const unsigned short* __restrict__ BL1, int K1, int f1,
    const unsigned short* __restrict__ AH2, const unsigned short* __restrict__ AL2,
    const unsigned short* __restrict__ BH2, const unsigned short* __restrict__ BL2, int K2, int f2,
    unsigned short* __restrict__ outH, unsigned short* __restrict__ outL,
    float* __restrict__ outF, int Nout, int EPI)
{
  __shared__ __align__(16) unsigned short SM[32768];   // 64 KB
  unsigned short* Ah = SM;            // [2][4096]
  unsigned short* Al = SM + 8192;
  unsigned short* Bh = SM + 16384;
  unsigned short* Bl = SM + 24576;

  const int tid = threadIdx.x;
  const int mb = blockIdx.x, nb = blockIdx.y;
  const int l = tid & 63, w = tid >> 6;
  const int wr = w >> 1, wc = w & 1;
  const int fr = l & 15, fq = l >> 4;

  f32x4 acc[4][4];
  #pragma unroll
  for (int m = 0; m < 4; m++)
    #pragma unroll
    for (int n = 0; n < 4; n++) acc[m][n] = f32x4{0.f, 0.f, 0.f, 0.f};

  const int nkt = (K1 + K2) >> 5;

  auto STAGE = [&](int buf, int kt){
    const int k0 = kt << 5;
    const unsigned short *aH, *aL, *bH, *bL; int st, kk, flg;
    if (k0 < K1){ aH = AH1; aL = AL1; bH = BH1; bL = BL1; st = K1; kk = k0; flg = f1; }
    else        { aH = AH2; aL = AL2; bH = BH2; bL = BL2; st = K2; kk = k0 - K1; flg = f2; }
    #pragma unroll
    for (int it = 0; it < 2; it++){
      int seg = tid + it * 256;
      int r = seg >> 2, c4 = seg & 3;
      int sc = (c4 ^ (r & 3)) << 3;
      size_t go = (size_t)(mb*128 + r) * st + kk + sc;
      size_t gb = (size_t)(nb*128 + r) * st + kk + sc;
      int lo = buf*4096 + r*32 + c4*8;
      GLD16(aH + go, Ah + lo);
      if (flg & 1) GLD16(aL + go, Al + lo);
      GLD16(bH + gb, Bh + lo);
      if (flg & 2) GLD16(bL + gb, Bl + lo);
    }
  };

  STAGE(0, 0);
  __syncthreads();

  for (int kt = 0; kt < nkt; kt++){
    const int cur = kt & 1;
    const int flg = ((kt << 5) < K1) ? f1 : f2;
    if (kt + 1 < nkt) STAGE(cur ^ 1, kt + 1);

    bf16x8 a_h[4], a_l[4], b_h[4], b_l[4];
    #pragma unroll
    for (int m = 0; m < 4; m++){
      int lra = wr*64 + m*16 + fr;
      int ra = cur*4096 + lra*32 + ((fq ^ (lra & 3)) << 3);
      a_h[m] = *(const bf16x8*)&Ah[ra];
      if (flg & 1) a_l[m] = *(const bf16x8*)&Al[ra];
      int lrb = wc*64 + m*16 + fr;
      int rb = cur*4096 + lrb*32 + ((fq ^ (lrb & 3)) << 3);
      b_h[m] = *(const bf16x8*)&Bh[rb];
      if (flg & 2) b_l[m] = *(const bf16x8*)&Bl[rb];
    }
    __builtin_amdgcn_s_setprio(1);
    #pragma unroll
    for (int m = 0; m < 4; m++)
      #pragma unroll
      for (int n = 0; n < 4; n++)
        acc[m][n] = __builtin_amdgcn_mfma_f32_16x16x32_bf16(a_h[m], b_h[n], acc[m][n], 0, 0, 0);
    if (flg & 1)
      #pragma unroll
      for (int m = 0; m < 4; m++)
        #pragma unroll
        for (int n = 0; n < 4; n++)
          acc[m][n] = __builtin_amdgcn_mfma_f32_16x16x32_bf16(a_l[m], b_h[n], acc[m][n], 0, 0, 0);
    if (flg & 2)
      #pragma unroll
      for (int m = 0; m < 4; m++)
        #pragma unroll
        for (int n = 0; n < 4; n++)
          acc[m][n] = __builtin_amdgcn_mfma_f32_16x16x32_bf16(a_h[m], b_l[n], acc[m][n], 0, 0, 0);
    __builtin_amdgcn_s_setprio(0);

    __syncthreads();
  }

  // ---- coalesced epilogue via LDS (128x128 f32 = 64 KB) ----
  float* fl = (float*)SM;
  #pragma unroll
  for (int m = 0; m < 4; m++)
    #pragma unroll
    for (int n = 0; n < 4; n++)
      #pragma unroll
      for (int j = 0; j < 4; j++)
        fl[(wr*64 + m*16 + fq*4 + j)*128 + wc*64 + n*16 + fr] = acc[m][n][j];
  __syncthreads();
  #pragma unroll
  for (int it = 0; it < 8; it++){
    int task = tid + (it << 8);
    int rl = task >> 4, cg = task & 15;
    float4 v0 = *(const float4*)&fl[rl*128 + cg*8];
    float4 v1 = *(const float4*)&fl[rl*128 + cg*8 + 4];
    size_t o = (size_t)(mb*128 + rl) * Nout + nb*128 + cg*8;
    if (EPI == 0){
      *(float4*)(outF + o)     = v0;
      *(float4*)(outF + o + 4) = v1;
    } else {
      float xv[8] = {v0.x,v0.y,v0.z,v0.w,v1.x,v1.y,v1.z,v1.w};
      union { unsigned short us[8]; uint4 v; } ph, pl;
      #pragma unroll
      for (int e = 0; e < 8; e++){
        float x = xv[e];
        if (EPI == 2)      x = x / (1.f + __expf(-x));
        else if (EPI == 3) x = fmaxf(x, 0.f);
        ph.us[e] = f2bf(x);
        pl.us[e] = f2bf(x - bf2f(ph.us[e]));
      }
      *(uint4*)(outH + o) = ph.v;
      if (outL) *(uint4*)(outL + o) = pl.v;
    }
  }
}

// ---------------- scan kernels ----------------
__global__ __launch_bounds__(256) void scan_ends(const float* __restrict__ bu,
                                                 const float* __restrict__ lre,
                                                 const float* __restrict__ lim,
                                                 float2* __restrict__ ends){
  const int s = threadIdx.x;
  const int b = blockIdx.x >> 6;
  const int c = blockIdx.x & 63;
  const float lr = lre[s], li = lim[s];
  float hr = 0.f, hi = 0.f;
  const float* p = bu + ((size_t)b*TT + (size_t)c*CLEN)*SS + s;
  #pragma unroll 8
  for (int t = 0; t < CLEN; t++){
    float x  = p[(size_t)t * SS];
    float nr = fmaf(lr, hr, fmaf(-li, hi, x));
    float ni = fmaf(lr, hi, li * hr);
    hr = nr; hi = ni;
  }
  ends[((size_t)b*NCH + c)*SS + s] = make_float2(hr, hi);
}

__global__ __launch_bounds__(256) void scan_carries(const float2* __restrict__ ends,
                                                    const float* __restrict__ lre,
                                                    const float* __restrict__ lim,
                                                    float2* __restrict__ carryin){
  const int idx = blockIdx.x * 256 + threadIdx.x;
  const int b = idx >> 8;
  const int s = idx & 255;
  float pr = lre[s], pi = lim[s];
  #pragma unroll
  for (int q = 0; q < 6; q++){
    float nr = pr*pr - pi*pi;
    float ni = 2.f * pr * pi;
    pr = nr; pi = ni;
  }
  float hr = 0.f, hi = 0.f;
  for (int c = 0; c < NCH; c++){
    size_t o = ((size_t)b*NCH + c)*SS + s;
    carryin[o] = make_float2(hr, hi);
    float2 e = ends[o];
    float nr = fmaf(pr, hr, fmaf(-pi, hi, e.x));
    float ni = fmaf(pr, hi, fmaf(pi, hr, e.y));
    hr = nr; hi = ni;
  }
}

__global__ __launch_bounds__(256) void scan_apply(const float* __restrict__ bu,
                                                  const float* __restrict__ lre,
                                                  const float* __restrict__ lim,
                                                  const float2* __restrict__ carryin,
                                                  unsigned short* __restrict__ RehH,
                                                  unsigned short* __restrict__ RehL){
  const int s = threadIdx.x;
  const int b = blockIdx.x >> 6;
  const int c = blockIdx.x & 63;
  const float lr = lre[s], li = lim[s];
  float2 h0 = carryin[((size_t)b*NCH + c)*SS + s];
  float hr = h0.x, hi = h0.y;
  const size_t base = ((size_t)b*TT + (size_t)c*CLEN)*SS + s;
  #pragma unroll 4
  for (int t = 0; t < CLEN; t++){
    float x  = bu[base + (size_t)t * SS];
    float nr = fmaf(lr, hr, fmaf(-li, hi, x));
    float ni = fmaf(lr, hi, li * hr);
    hr = nr; hi = ni;
    unsigned short h = f2bf(hr);
    RehH[base + (size_t)t * SS] = h;
    RehL[base + (size_t)t * SS] = f2bf(hr - bf2f(h));
  }
}

// ---------------- host-side segment builders ----------------
static void seg_clear(SegDesc& sd){
  for (int i = 0; i < 6; i++){ sd.a[i]=nullptr; sd.b[i]=nullptr; sd.tiles[i]=0; sd.stride[i]=0; }
}
static int seg_add(SegDesc& sd, int at,
                   const unsigned short* a, const unsigned short* b, int K){
  sd.a[at]=a; sd.b[at]=b; sd.tiles[at]=K>>6; sd.stride[at]=K;
  return K>>6;
}

extern "C" void kernel_launch(void* const* d_in, const int* in_sizes, int n_in,
                              void* d_out, int out_size, void* d_ws, size_t ws_size,
                              hipStream_t stream){
  const float* inp = (const float*)d_in[0];
  const float* lre = (const float*)d_in[1];
  const float* lim = (const float*)d_in[2];
  const float* Bm  = (const float*)d_in[3];
  const float* Cm  = (const float*)d_in[4];
  const float* Dm  = (const float*)d_in[5];
  const float* W1  = (const float*)d_in[6];
  const float* W2  = (const float*)d_in[7];
  const float* W3  = (const float*)d_in[8];
  const float* Wl  = (const float*)d_in[9];
  float* out = (float*)d_out;

  char* ws = (char*)d_ws;
  size_t off = 0;
  auto alloc = [&](size_t bytes)->char*{
    char* p = ws + off; off += (bytes + 255) & ~(size_t)255; return p;
  };
  unsigned short* inH = (unsigned short*)alloc((size_t)BT*UU*2);
  unsigned short* inL = (unsigned short*)alloc((size_t)BT*UU*2);
  unsigned short* BwH = (unsigned short*)alloc((size_t)SS*UU*2);
  unsigned short* BwL = (unsigned short*)alloc((size_t)SS*UU*2);
  unsigned short* CH_ = (unsigned short*)alloc((size_t)OO*SS*2);
  unsigned short* CL_ = (unsigned short*)alloc((size_t)OO*SS*2);
  unsigned short* DH_ = (unsigned short*)alloc((size_t)OO*UU*2);
  unsigned short* DL_ = (unsigned short*)alloc((size_t)OO*UU*2);
  unsigned short* W1H = (unsigned short*)alloc((size_t)HH*OO*2);
  unsigned short* W1L = (unsigned short*)alloc((size_t)HH*OO*2);
  unsigned short* W2H = (unsigned short*)alloc((size_t)HH*HH*2);
  unsigned short* W2L = (unsigned short*)alloc((size_t)HH*HH*2);
  unsigned short* W3H = (unsigned short*)alloc((size_t)OO*HH*2);
  unsigned short* W3L = (unsigned short*)alloc((size_t)OO*HH*2);
  unsigned short* WlH = (unsigned short*)alloc((size_t)OO*UU*2);
  unsigned short* WlL = (unsigned short*)alloc((size_t)OO*UU*2);
  float2* ends    = (float2*)alloc((size_t)BSZ*NCH*SS*8);
  float2* carryin = (float2*)alloc((size_t)BSZ*NCH*SS*8);
  char* R1 = alloc((size_t)BT*SS*4);     // 64 MB: bu -> z1 (bf16, 64 MB)
  char* R2 = alloc((size_t)BT*SS*4);     // 64 MB: Reh H+L -> z2 (bf16, 64 MB)
  unsigned short* yH = (unsigned short*)alloc((size_t)BT*OO*2);
  unsigned short* yL = (unsigned short*)alloc((size_t)BT*OO*2);
  if (off > ws_size) return;

  float* bu = (float*)R1;
  unsigned short* RehH = (unsigned short*)R2;
  unsigned short* RehL = (unsigned short*)(R2 + (size_t)BT*SS*2);
  unsigned short* z1H = (unsigned short*)R1;   // after bu is dead
  unsigned short* z2H = (unsigned short*)R2;   // after Reh is dead

  // ---- split input + weights into bf16 hi/lo planes ----
  split_k<<<(BT*UU/4 + 255)/256, 256, 0, stream>>>(inp, inH, inL, BT*UU/4);
  split_k<<<(SS*UU/4 + 255)/256, 256, 0, stream>>>(Bm, BwH, BwL, SS*UU/4);
  split_k<<<(OO*SS/4 + 255)/256, 256, 0, stream>>>(Cm, CH_, CL_, OO*SS/4);
  split_k<<<(OO*UU/4 + 255)/256, 256, 0, stream>>>(Dm, DH_, DL_, OO*UU/4);
  split_k<<<(HH*OO/4 + 255)/256, 256, 0, stream>>>(W1, W1H, W1L, HH*OO/4);
  split_k<<<(HH*HH/4 + 255)/256, 256, 0, stream>>>(W2, W2H, W2L, HH*HH/4);
  split_k<<<(OO*HH/4 + 255)/256, 256, 0, stream>>>(W3, W3H, W3L, OO*HH/4);
  split_k<<<(OO*UU/4 + 255)/256, 256, 0, stream>>>(Wl, WlH, WlL, OO*UU/4);

  SegDesc sd; int NT;

  // ---- bu = input @ B^T (3-term, fp32 out for the scan) ----
  seg_clear(sd);
  NT  = seg_add(sd, 0, inH, BwH, UU);
  NT += seg_add(sd, 1, inL, BwH, UU);
  NT += seg_add(sd, 2, inH, BwL, UU);          // NT = 6
  gemm256<<<(BT/256)*(SS/256), 512, 0, stream>>>(sd, NT, nullptr, nullptr, bu, SS, 0, SS/256);

  // ---- diagonal complex scan ----
  scan_ends<<<BSZ*NCH, 256, 0, stream>>>(bu, lre, lim, ends);
  scan_carries<<<(BSZ*SS)/256, 256, 0, stream>>>(ends, lre, lim, carryin);
  scan_apply<<<BSZ*NCH, 256, 0, stream>>>(bu, lre, lim, carryin, RehH, RehL);

  // ---- y = Re(h)@C^T + in@D^T (3-term both, split H+L out) ----
  gemm_split<<<dim3(BT/128, OO/128), 256, 0, stream>>>(
      RehH, RehL, CH_, CL_, SS, 3,
      inH,  inL,  DH_, DL_, UU, 3,
      yH, yL, nullptr, OO, 1);

  // ---- z1 = silu(y @ W1^T): 2-term (yh+yl)*W1h, bf16-only out ----
  seg_clear(sd);
  NT  = seg_add(sd, 0, yH, W1H, OO);
  NT += seg_add(sd, 1, yL, W1H, OO);           // NT = 4
  gemm256<<<(BT/256)*(HH/256), 512, 0, stream>>>(sd, NT, z1H, nullptr, nullptr, HH, 2, HH/256);

  // ---- z2 = relu(z1 @ W2^T): 1-term, bf16-only out ----
  seg_clear(sd);
  NT = seg_add(sd, 0, z1H, W2H, HH);           // NT = 8
  gemm256<<<(BT/256)*(HH/256), 512, 0, stream>>>(sd, NT, z2H, nullptr, nullptr, HH, 3, HH/256);

  // ---- out = z2 @ W3^T (2-term: z2h*(W3h+W3l)) + in @ Wlin^T (3-term) ----
  gemm_split<<<dim3(BT/128, OO/128), 256, 0, stream>>>(
      z2H, z2H, W3H, W3L, HH, 2,
      inH, inL, WlH, WlL, UU, 3,
      nullptr, nullptr, out, OO, 0);
}

// Round 7
// 271.720 us; speedup vs baseline: 1.9999x; 1.1121x over previous
//
#include <hip/hip_runtime.h>
#include <hip/hip_bf16.h>

#define BSZ 16
#define TT 4096
#define UU 128
#define OO 128
#define SS 256
#define HH 512
#define BT (BSZ*TT)      // 65536 rows
#define CLEN 64          // scan chunk length
#define NCH (TT/CLEN)    // 64 chunks per sequence

using bf16x8 = __attribute__((ext_vector_type(8))) short;
using f32x4  = __attribute__((ext_vector_type(4))) float;

__device__ __forceinline__ unsigned short f2bf(float x){
  union { float f; unsigned int u; } v; v.f = x;
  unsigned int r = v.u + 0x7fffu + ((v.u >> 16) & 1u);
  return (unsigned short)(r >> 16);
}
__device__ __forceinline__ float bf2f(unsigned short h){
  union { float f; unsigned int u; } v; v.u = ((unsigned int)h) << 16;
  return v.f;
}

#define GLD16(g, s) __builtin_amdgcn_global_load_lds( \
    (const __attribute__((address_space(1))) unsigned int*)(g), \
    (__attribute__((address_space(3))) unsigned int*)(s), 16, 0, 0)

#define SBAR() do{ __builtin_amdgcn_sched_barrier(0); \
                   __builtin_amdgcn_s_barrier(); \
                   __builtin_amdgcn_sched_barrier(0); }while(0)

// ---------------- split fp32 -> (hi, lo) bf16 planes ----------------
__global__ __launch_bounds__(256) void split_k(const float* __restrict__ x,
                                               unsigned short* __restrict__ H,
                                               unsigned short* __restrict__ L, int n4){
  int i = blockIdx.x * 256 + threadIdx.x;
  if (i >= n4) return;
  float4 v = ((const float4*)x)[i];
  unsigned short h0 = f2bf(v.x), h1 = f2bf(v.y), h2 = f2bf(v.z), h3 = f2bf(v.w);
  ushort4 hh = make_ushort4(h0, h1, h2, h3);
  ushort4 ll = make_ushort4(f2bf(v.x - bf2f(h0)), f2bf(v.y - bf2f(h1)),
                            f2bf(v.z - bf2f(h2)), f2bf(v.w - bf2f(h3)));
  ((ushort4*)H)[i] = hh;
  ((ushort4*)L)[i] = ll;
}

struct SegDesc {
  const unsigned short* a[6];
  const unsigned short* b[6];
  int tiles[6];
  int stride[6];
};

// =================== gemm256 (bu): 8-phase 256x256 + fused chunk-ends ===================
__global__ __launch_bounds__(512, 1) void gemm256(SegDesc sd, int NT,
    unsigned short* __restrict__ outH, unsigned short* __restrict__ outL,
    float* __restrict__ outF, int Nout, int EPI, int gx,
    const float* __restrict__ lre, const float* __restrict__ lim,
    float2* __restrict__ ends)
{
  __shared__ __align__(16) unsigned short LDS[65536];   // 128 KB

  const int tid = threadIdx.x;
  const int l = tid & 63, w = tid >> 6;
  const int wr = w >> 2, wc = w & 3;
  const int fr = l & 15, fq = l >> 4;

  const int nwg = gridDim.x, bid = blockIdx.x;
  const int q8 = nwg >> 3;
  const int swz = (bid & 7) * q8 + (bid >> 3);
  const int nb = swz % gx, mb = swz / gx;

  const int total_u = 4 * NT;

  auto stage_unit = [&](int u){
    const int Tu = u >> 2, ksu = (u >> 1) & 1, isB = u & 1;
    const unsigned short* p = sd.a[0]; int st = sd.stride[0], kb = 0, cum = 0;
    #pragma unroll
    for (int s = 0; s < 6; s++){
      int tl = sd.tiles[s];
      if (tl && Tu >= cum && Tu < cum + tl){ p = isB ? sd.b[s] : sd.a[s]; st = sd.stride[s]; kb = cum; }
      cum += tl;
    }
    const int kk = ((Tu - kb) << 6) + (ksu << 5);
    const int row0 = (isB ? nb : mb) << 8;
    unsigned short* dst = &LDS[(isB ? 32768 : 0) + (((u >> 1) & 3) << 13)];
    #pragma unroll
    for (int j = 0; j < 2; j++){
      int seg = tid + (j << 9);
      int r = seg >> 2, c4 = seg & 3;
      int sc = (c4 ^ ((r >> 1) & 3)) << 3;
      GLD16(p + (size_t)(row0 + r) * st + kk + sc, dst + seg * 8);
    }
  };

  f32x4 acc[8][4];
  #pragma unroll
  for (int m = 0; m < 8; m++)
    #pragma unroll
    for (int n = 0; n < 4; n++) acc[m][n] = f32x4{0.f, 0.f, 0.f, 0.f};

  for (int u = 0; u < 6 && u < total_u; u++) stage_unit(u);
  if (total_u > 6) asm volatile("s_waitcnt vmcnt(4)" ::: "memory");
  else             asm volatile("s_waitcnt vmcnt(0)" ::: "memory");
  SBAR();

  bf16x8 Bfr[4];
  for (int T = 0; T < NT; T++){
    #pragma unroll
    for (int q = 0; q < 4; q++){
      const int mh = q & 1, ks = q >> 1;
      const int abase = (((2*T + ks) & 3) << 13);
      const int bbase = 32768 + abase;
      bf16x8 Afr[4];
      #pragma unroll
      for (int m = 0; m < 4; m++){
        int row = wr*128 + mh*64 + m*16 + fr;
        Afr[m] = *(const bf16x8*)&LDS[abase + row*32 + ((fq ^ ((row>>1)&3)) << 3)];
      }
      if (mh == 0){
        #pragma unroll
        for (int n = 0; n < 4; n++){
          int row = wc*64 + n*16 + fr;
          Bfr[n] = *(const bf16x8*)&LDS[bbase + row*32 + ((fq ^ ((row>>1)&3)) << 3)];
        }
      }
      int u = 4*T + q + 6;
      if (u < total_u) stage_unit(u);
      if (q == 3){
        if (T < NT-2)       asm volatile("s_waitcnt vmcnt(4)" ::: "memory");
        else if (T == NT-2) asm volatile("s_waitcnt vmcnt(0)" ::: "memory");
      }
      SBAR();
      __builtin_amdgcn_s_setprio(1);
      #pragma unroll
      for (int m = 0; m < 4; m++)
        #pragma unroll
        for (int n = 0; n < 4; n++)
          acc[mh*4+m][n] = __builtin_amdgcn_mfma_f32_16x16x32_bf16(Afr[m], Bfr[n], acc[mh*4+m][n], 0, 0, 0);
      __builtin_amdgcn_s_setprio(0);
      SBAR();
    }
  }

  // ---- epilogue: acc -> LDS f32 half [128][256]; + fused chunk-end scans ----
  float* fl = (float*)LDS;
  #pragma unroll
  for (int h = 0; h < 2; h++){
    if (wr == h){
      #pragma unroll
      for (int mf = 0; mf < 8; mf++)
        #pragma unroll
        for (int n = 0; n < 4; n++)
          #pragma unroll
          for (int j = 0; j < 4; j++)
            fl[(mf*16 + fq*4 + j)*256 + wc*64 + n*16 + fr] = acc[mf][n][j];
    }
    __syncthreads();
    if (ends){
      int s = tid & 255, cp = tid >> 8;
      int b = mb >> 4, chunk = ((mb & 15) << 2) + (h << 1) + cp;
      float lr = lre[s], li = lim[s];
      float hr = 0.f, hi2 = 0.f;
      for (int t = 0; t < 64; t++){
        float x = fl[(cp*64 + t)*256 + s];
        float nr = fmaf(lr, hr, fmaf(-li, hi2, x));
        float ni = fmaf(lr, hi2, li * hr);
        hr = nr; hi2 = ni;
      }
      ends[((size_t)(b*NCH + chunk))*SS + s] = make_float2(hr, hi2);
    }
    #pragma unroll
    for (int it = 0; it < 8; it++){
      int task = tid + (it << 9);
      int rl = task >> 5, cg = task & 31;
      float4 v0 = *(const float4*)&fl[rl*256 + cg*8];
      float4 v1 = *(const float4*)&fl[rl*256 + cg*8 + 4];
      size_t o = (size_t)(mb*256 + h*128 + rl) * Nout + nb*256 + cg*8;
      if (EPI == 0){
        *(float4*)(outF + o)     = v0;
        *(float4*)(outF + o + 4) = v1;
      } else {
        float xv[8] = {v0.x,v0.y,v0.z,v0.w,v1.x,v1.y,v1.z,v1.w};
        union { unsigned short us[8]; uint4 v; } ph, pl;
        #pragma unroll
        for (int e = 0; e < 8; e++){
          float x = xv[e];
          ph.us[e] = f2bf(x);
          pl.us[e] = f2bf(x - bf2f(ph.us[e]));
        }
        *(uint4*)(outH + o) = ph.v;
        if (outL) *(uint4*)(outL + o) = pl.v;
      }
    }
    __syncthreads();
  }
}

// ---------------- scan carries (unchanged) ----------------
__global__ __launch_bounds__(256) void scan_carries(const float2* __restrict__ ends,
                                                    const float* __restrict__ lre,
                                                    const float* __restrict__ lim,
                                                    float2* __restrict__ carryin){
  const int idx = blockIdx.x * 256 + threadIdx.x;
  const int b = idx >> 8;
  const int s = idx & 255;
  float pr = lre[s], pi = lim[s];
  #pragma unroll
  for (int q = 0; q < 6; q++){
    float nr = pr*pr - pi*pi;
    float ni = 2.f * pr * pi;
    pr = nr; pi = ni;
  }
  float hr = 0.f, hi = 0.f;
  for (int c = 0; c < NCH; c++){
    size_t o = ((size_t)b*NCH + c)*SS + s;
    carryin[o] = make_float2(hr, hi);
    float2 e = ends[o];
    float nr = fmaf(pr, hr, fmaf(-pi, hi, e.x));
    float ni = fmaf(pr, hi, fmaf(pi, hr, e.y));
    hr = nr; hi = ni;
  }
}

// =================== mega: scan_apply + y + MLP + residual, all in LDS ===================
// Block = one chunk (64 rows). LDS regions (padded strides -> 2-way-free A reads):
//   A1 @0      : bu/Reh [64][528B]x2 planes (67584) -> later z1H [64][1040B] (66560)
//   A2 @67584  : in [64][272B]x2 -> y H/L -> z2H chunk (plane0) -> inH restage
//   WS @102400 : 2 x 16KB B-tile dbuf -> epilogue fp32 [64][128]
#define A1_OFF   0
#define A1_PS    528
#define A1_PL    33792
#define Z1_PS    1040
#define A2_OFF   67584
#define A2_PS    272
#define A2_PL    17408
#define WS_OFF   102400
#define WT_SZ    16384

__global__ __launch_bounds__(512, 1) void mega(
    const unsigned short* __restrict__ buH, const unsigned short* __restrict__ buL,
    const unsigned short* __restrict__ inH, const unsigned short* __restrict__ inL,
    const unsigned short* __restrict__ CHp, const unsigned short* __restrict__ CLp,
    const unsigned short* __restrict__ DHp, const unsigned short* __restrict__ DLp,
    const unsigned short* __restrict__ W1H,
    const unsigned short* __restrict__ W2H,
    const unsigned short* __restrict__ W3H, const unsigned short* __restrict__ W3L,
    const unsigned short* __restrict__ WlH, const unsigned short* __restrict__ WlL,
    const float* __restrict__ lre, const float* __restrict__ lim,
    const float2* __restrict__ carryin,
    float* __restrict__ out)
{
  __shared__ __align__(16) unsigned char LDS[135168];
  const int tid = threadIdx.x;
  const int l = tid & 63, w = tid >> 6;
  const int wr = w >> 1, wc = w & 1;     // 4 row-groups x 2 col-groups
  const int fr = l & 15, fq = l >> 4;
  const int g = blockIdx.x;
  const size_t r0 = (size_t)g * 64;

  // ---- stage bu(H,L) + in(H,L) via regs -> padded LDS ----
  {
    uint4 regs[12];
    #pragma unroll
    for (int k = 0; k < 8; k++){
      int seg = tid + (k << 9);
      int pl = seg >> 11, s2 = seg & 2047, r = s2 >> 5, c = s2 & 31;
      regs[k] = *(const uint4*)((pl ? buL : buH) + (r0 + r)*SS + c*8);
    }
    #pragma unroll
    for (int k = 0; k < 4; k++){
      int seg = tid + (k << 9);
      int pl = seg >> 10, s2 = seg & 1023, r = s2 >> 4, c = s2 & 15;
      regs[8+k] = *(const uint4*)((pl ? inL : inH) + (r0 + r)*UU + c*8);
    }
    #pragma unroll
    for (int k = 0; k < 8; k++){
      int seg = tid + (k << 9);
      int pl = seg >> 11, s2 = seg & 2047, r = s2 >> 5, c = s2 & 31;
      *(uint4*)(LDS + A1_OFF + pl*A1_PL + r*A1_PS + c*16) = regs[k];
    }
    #pragma unroll
    for (int k = 0; k < 4; k++){
      int seg = tid + (k << 9);
      int pl = seg >> 10, s2 = seg & 1023, r = s2 >> 4, c = s2 & 15;
      *(uint4*)(LDS + A2_OFF + pl*A2_PL + r*A2_PS + c*16) = regs[8+k];
    }
  }
  __syncthreads();

  // ---- in-LDS scan_apply (threads 0..255: one s each), in place ----
  if (tid < 256){
    int s = tid;
    int b = g >> 6, ch = g & 63;
    float lr = lre[s], li = lim[s];
    float2 c0 = carryin[((size_t)(b*NCH + ch))*SS + s];
    float hr = c0.x, hi = c0.y;
    unsigned short* ph = (unsigned short*)(LDS + A1_OFF);
    unsigned short* pl = (unsigned short*)(LDS + A1_OFF + A1_PL);
    for (int t = 0; t < 64; t++){
      int off = t*(A1_PS/2) + s;
      float x = bf2f(ph[off]) + bf2f(pl[off]);
      float nr = fmaf(lr, hr, fmaf(-li, hi, x));
      float ni = fmaf(lr, hi, li * hr);
      hr = nr; hi = ni;
      unsigned short hh = f2bf(hr);
      ph[off] = hh;
      pl[off] = f2bf(hr - bf2f(hh));
    }
  }
  __syncthreads();

  // ---- GEMM helpers ----
  auto stageB = [&](const unsigned short* Bsrc, int stride, int rowbase, int kcol, int buf){
    #pragma unroll
    for (int j = 0; j < 2; j++){
      int seg = tid + (j << 9);          // 1024 segs = [128 rows][8 chunks]
      int r = seg >> 3, c = seg & 7;
      GLD16(Bsrc + (size_t)(rowbase + r)*stride + kcol + ((c ^ (r & 7)) << 3),
            LDS + WS_OFF + buf*WT_SZ + seg*16);
    }
  };
  auto mfmaU = [&](int Abase, int APS, int kc, int buf, f32x4* ac){
    const unsigned char* Bb = LDS + WS_OFF + buf*WT_SZ;
    __builtin_amdgcn_s_setprio(1);
    #pragma unroll
    for (int ks = 0; ks < 2; ks++){
      bf16x8 a = *(const bf16x8*)(LDS + Abase + (wr*16 + fr)*APS + (kc + ks*32 + fq*8)*2);
      #pragma unroll
      for (int n = 0; n < 4; n++){
        int rn = wc*64 + n*16 + fr;
        int cb = ks*4 + fq;
        bf16x8 b = *(const bf16x8*)(Bb + rn*128 + ((cb ^ (rn & 7)) << 4));
        ac[n] = __builtin_amdgcn_mfma_f32_16x16x32_bf16(a, b, ac[n], 0, 0, 0);
      }
    }
    __builtin_amdgcn_s_setprio(0);
  };

  // ======== P-y: y = Reh@C^T (3t) + in@D^T (3t); 18 units ========
  f32x4 accY[4];
  #pragma unroll
  for (int n = 0; n < 4; n++) accY[n] = f32x4{0.f,0.f,0.f,0.f};
  {
    auto yStage = [&](int u, int buf){
      if (u < 12){ int term = u >> 2, kt = u & 3;
        stageB((term == 2) ? CLp : CHp, SS, 0, kt*64, buf); }
      else { int v = u - 12; int term = v >> 1, kt = v & 1;
        stageB((term == 2) ? DLp : DHp, UU, 0, kt*64, buf); }
    };
    yStage(0, 0);
    for (int u = 0; u < 18; u++){
      if (u + 1 < 18) yStage(u + 1, (u + 1) & 1);
      if (u + 1 < 18) asm volatile("s_waitcnt vmcnt(2)" ::: "memory");
      else            asm volatile("s_waitcnt vmcnt(0)" ::: "memory");
      SBAR();
      int Abase, APS, kc;
      if (u < 12){ int term = u >> 2, kt = u & 3;
        Abase = A1_OFF + ((term == 1) ? A1_PL : 0); APS = A1_PS; kc = kt*64; }
      else { int v = u - 12; int term = v >> 1, kt = v & 1;
        Abase = A2_OFF + ((term == 1) ? A2_PL : 0); APS = A2_PS; kc = kt*64; }
      mfmaU(Abase, APS, kc, u & 1, accY);
      SBAR();
    }
  }
  __syncthreads();
  // write y H/L over in-tile (A2)
  #pragma unroll
  for (int n = 0; n < 4; n++)
    #pragma unroll
    for (int j = 0; j < 4; j++){
      float v = accY[n][j];
      int row = wr*16 + fq*4 + j, col = wc*64 + n*16 + fr;
      unsigned short hh = f2bf(v);
      *(unsigned short*)(LDS + A2_OFF + row*A2_PS + col*2) = hh;
      *(unsigned short*)(LDS + A2_OFF + A2_PL + row*A2_PS + col*2) = f2bf(v - bf2f(hh));
    }
  __syncthreads();

  // ======== P-W1: z1 = silu(y @ W1^T), N=512 in 4 chunks; 4 units each ========
  for (int nb = 0; nb < 4; nb++){
    f32x4 acc1[4];
    #pragma unroll
    for (int n = 0; n < 4; n++) acc1[n] = f32x4{0.f,0.f,0.f,0.f};
    stageB(W1H, UU, nb*128, 0, 0);
    for (int u = 0; u < 4; u++){
      if (u + 1 < 4) stageB(W1H, UU, nb*128, (u + 1 == 1 || u + 1 == 3) ? 64 : 0, (u + 1) & 1);
      if (u + 1 < 4) asm volatile("s_waitcnt vmcnt(2)" ::: "memory");
      else           asm volatile("s_waitcnt vmcnt(0)" ::: "memory");
      SBAR();
      int term = u >> 1, kt = u & 1;
      mfmaU(A2_OFF + (term ? A2_PL : 0), A2_PS, kt*64, u & 1, acc1);
      SBAR();
    }
    __syncthreads();
    #pragma unroll
    for (int n = 0; n < 4; n++)
      #pragma unroll
      for (int j = 0; j < 4; j++){
        float v = acc1[n][j];
        v = v / (1.f + __expf(-v));          // silu
        int row = wr*16 + fq*4 + j, col = nb*128 + wc*64 + n*16 + fr;
        *(unsigned short*)(LDS + A1_OFF + row*Z1_PS + col*2) = f2bf(v);
      }
    __syncthreads();
  }

  // ======== P-W2+W3: stream z2 chunks; accumulate out ========
  f32x4 accO[4];
  #pragma unroll
  for (int n = 0; n < 4; n++) accO[n] = f32x4{0.f,0.f,0.f,0.f};
  for (int nb = 0; nb < 4; nb++){
    f32x4 acc2[4];
    #pragma unroll
    for (int n = 0; n < 4; n++) acc2[n] = f32x4{0.f,0.f,0.f,0.f};
    stageB(W2H, HH, nb*128, 0, 0);
    for (int u = 0; u < 8; u++){
      if (u + 1 < 8) stageB(W2H, HH, nb*128, (u + 1)*64, (u + 1) & 1);
      if (u + 1 < 8) asm volatile("s_waitcnt vmcnt(2)" ::: "memory");
      else           asm volatile("s_waitcnt vmcnt(0)" ::: "memory");
      SBAR();
      mfmaU(A1_OFF, Z1_PS, u*64, u & 1, acc2);
      SBAR();
    }
    __syncthreads();
    #pragma unroll
    for (int n = 0; n < 4; n++)
      #pragma unroll
      for (int j = 0; j < 4; j++){
        float v = fmaxf(acc2[n][j], 0.f);    // relu
        int row = wr*16 + fq*4 + j, col = wc*64 + n*16 + fr;
        *(unsigned short*)(LDS + A2_OFF + row*A2_PS + col*2) = f2bf(v);
      }
    __syncthreads();
    // out += z2_chunk @ W3[:, nb-chunk]^T  (2-term on W3)
    auto w3Stage = [&](int u, int buf){
      int term = u >> 1, kt = u & 1;
      stageB(term ? W3L : W3H, HH, 0, nb*128 + kt*64, buf);
    };
    w3Stage(0, 0);
    for (int u = 0; u < 4; u++){
      if (u + 1 < 4) w3Stage(u + 1, (u + 1) & 1);
      if (u + 1 < 4) asm volatile("s_waitcnt vmcnt(2)" ::: "memory");
      else           asm volatile("s_waitcnt vmcnt(0)" ::: "memory");
      SBAR();
      mfmaU(A2_OFF, A2_PS, (u & 1)*64, u & 1, accO);
      SBAR();
    }
    __syncthreads();
  }

  // ======== P-Wl: out += in @ Wl^T (2-term on Wl) ========
  {
    uint4 rr[2];
    #pragma unroll
    for (int k = 0; k < 2; k++){
      int seg = tid + (k << 9);
      int r = seg >> 4, c = seg & 15;
      rr[k] = *(const uint4*)(inH + (r0 + r)*UU + c*8);
    }
    __syncthreads();
    #pragma unroll
    for (int k = 0; k < 2; k++){
      int seg = tid + (k << 9);
      int r = seg >> 4, c = seg & 15;
      *(uint4*)(LDS + A2_OFF + r*A2_PS + c*16) = rr[k];
    }
    __syncthreads();
    auto wlStage = [&](int u, int buf){
      int term = u >> 1, kt = u & 1;
      stageB(term ? WlL : WlH, UU, 0, kt*64, buf);
    };
    wlStage(0, 0);
    for (int u = 0; u < 4; u++){
      if (u + 1 < 4) wlStage(u + 1, (u + 1) & 1);
      if (u + 1 < 4) asm volatile("s_waitcnt vmcnt(2)" ::: "memory");
      else           asm volatile("s_waitcnt vmcnt(0)" ::: "memory");
      SBAR();
      mfmaU(A2_OFF, A2_PS, (u & 1)*64, u & 1, accO);
      SBAR();
    }
  }

  // ======== epilogue: accO -> LDS fp32 -> coalesced stores ========
  __syncthreads();
  float* EP = (float*)(LDS + WS_OFF);
  #pragma unroll
  for (int n = 0; n < 4; n++)
    #pragma unroll
    for (int j = 0; j < 4; j++)
      EP[(wr*16 + fq*4 + j)*128 + wc*64 + n*16 + fr] = accO[n][j];
  __syncthreads();
  #pragma unroll
  for (int k2 = 0; k2 < 4; k2++){
    int idx4 = tid + k2*512;
    int foff = idx4*4;
    int row = foff >> 7, col = foff & 127;
    *(float4*)(out + (r0 + row)*OO + col) = *(const float4*)(EP + foff);
  }
}

// ---------------- host-side segment builders ----------------
static void seg_clear(SegDesc& sd){
  for (int i = 0; i < 6; i++){ sd.a[i]=nullptr; sd.b[i]=nullptr; sd.tiles[i]=0; sd.stride[i]=0; }
}
static int seg_add(SegDesc& sd, int at,
                   const unsigned short* a, const unsigned short* b, int K){
  sd.a[at]=a; sd.b[at]=b; sd.tiles[at]=K>>6; sd.stride[at]=K;
  return K>>6;
}

extern "C" void kernel_launch(void* const* d_in, const int* in_sizes, int n_in,
                              void* d_out, int out_size, void* d_ws, size_t ws_size,
                              hipStream_t stream){
  const float* inp = (const float*)d_in[0];
  const float* lre = (const float*)d_in[1];
  const float* lim = (const float*)d_in[2];
  const float* Bm  = (const float*)d_in[3];
  const float* Cm  = (const float*)d_in[4];
  const float* Dm  = (const float*)d_in[5];
  const float* W1  = (const float*)d_in[6];
  const float* W2  = (const float*)d_in[7];
  const float* W3  = (const float*)d_in[8];
  const float* Wl  = (const float*)d_in[9];
  float* out = (float*)d_out;

  char* ws = (char*)d_ws;
  size_t off = 0;
  auto alloc = [&](size_t bytes)->char*{
    char* p = ws + off; off += (bytes + 255) & ~(size_t)255; return p;
  };
  unsigned short* inH = (unsigned short*)alloc((size_t)BT*UU*2);
  unsigned short* inL = (unsigned short*)alloc((size_t)BT*UU*2);
  unsigned short* buH = (unsigned short*)alloc((size_t)BT*SS*2);
  unsigned short* buL = (unsigned short*)alloc((size_t)BT*SS*2);
  unsigned short* BwH = (unsigned short*)alloc((size_t)SS*UU*2);
  unsigned short* BwL = (unsigned short*)alloc((size_t)SS*UU*2);
  unsigned short* CH_ = (unsigned short*)alloc((size_t)OO*SS*2);
  unsigned short* CL_ = (unsigned short*)alloc((size_t)OO*SS*2);
  unsigned short* DH_ = (unsigned short*)alloc((size_t)OO*UU*2);
  unsigned short* DL_ = (unsigned short*)alloc((size_t)OO*UU*2);
  unsigned short* W1H = (unsigned short*)alloc((size_t)HH*OO*2);
  unsigned short* W1L = (unsigned short*)alloc((size_t)HH*OO*2);
  unsigned short* W2H = (unsigned short*)alloc((size_t)HH*HH*2);
  unsigned short* W2L = (unsigned short*)alloc((size_t)HH*HH*2);
  unsigned short* W3H = (unsigned short*)alloc((size_t)OO*HH*2);
  unsigned short* W3L = (unsigned short*)alloc((size_t)OO*HH*2);
  unsigned short* WlH = (unsigned short*)alloc((size_t)OO*UU*2);
  unsigned short* WlL = (unsigned short*)alloc((size_t)OO*UU*2);
  float2* ends    = (float2*)alloc((size_t)BSZ*NCH*SS*8);
  float2* carryin = (float2*)alloc((size_t)BSZ*NCH*SS*8);
  if (off > ws_size) return;

  // ---- split input + weights into bf16 hi/lo planes ----
  split_k<<<(BT*UU/4 + 255)/256, 256, 0, stream>>>(inp, inH, inL, BT*UU/4);
  split_k<<<(SS*UU/4 + 255)/256, 256, 0, stream>>>(Bm, BwH, BwL, SS*UU/4);
  split_k<<<(OO*SS/4 + 255)/256, 256, 0, stream>>>(Cm, CH_, CL_, OO*SS/4);
  split_k<<<(OO*UU/4 + 255)/256, 256, 0, stream>>>(Dm, DH_, DL_, OO*UU/4);
  split_k<<<(HH*OO/4 + 255)/256, 256, 0, stream>>>(W1, W1H, W1L, HH*OO/4);
  split_k<<<(HH*HH/4 + 255)/256, 256, 0, stream>>>(W2, W2H, W2L, HH*HH/4);
  split_k<<<(OO*HH/4 + 255)/256, 256, 0, stream>>>(W3, W3H, W3L, OO*HH/4);
  split_k<<<(OO*UU/4 + 255)/256, 256, 0, stream>>>(Wl, WlH, WlL, OO*UU/4);

  // ---- bu = input @ B^T (3-term), bf16 H/L out + fused chunk-end scans ----
  SegDesc sd; int NT;
  seg_clear(sd);
  NT  = seg_add(sd, 0, inH, BwH, UU);
  NT += seg_add(sd, 1, inH, BwL, UU);    // inH segments adjacent (L2-hot re-read)
  NT += seg_add(sd, 2, inL, BwH, UU);    // NT = 6
  gemm256<<<(BT/256)*(SS/256), 512, 0, stream>>>(sd, NT, buH, buL, nullptr, SS, 1, SS/256,
                                                 lre, lim, ends);

  // ---- cross-chunk carries ----
  scan_carries<<<(BSZ*SS)/256, 256, 0, stream>>>(ends, lre, lim, carryin);

  // ---- mega: scan_apply + y + W1 + W2 + W3 + Wlin, all fused ----
  mega<<<BT/64, 512, 0, stream>>>(buH, buL, inH, inL,
                                  CH_, CL_, DH_, DL_,
                                  W1H, W2H, W3H, W3L, WlH, WlL,
                                  lre, lim, carryin, out);
}

// Round 9
// 255.478 us; speedup vs baseline: 2.1271x; 1.0636x over previous
//
#include <hip/hip_runtime.h>
#include <hip/hip_bf16.h>

#define BSZ 16
#define TT 4096
#define UU 128
#define OO 128
#define SS 256
#define HH 512
#define BT (BSZ*TT)      // 65536 rows
#define CLEN 64          // scan chunk length
#define NCH (TT/CLEN)    // 64 chunks per sequence

using bf16x8 = __attribute__((ext_vector_type(8))) short;
using f32x4  = __attribute__((ext_vector_type(4))) float;

__device__ __forceinline__ unsigned short f2bf(float x){
  union { float f; unsigned int u; } v; v.f = x;
  unsigned int r = v.u + 0x7fffu + ((v.u >> 16) & 1u);
  return (unsigned short)(r >> 16);
}
__device__ __forceinline__ float bf2f(unsigned short h){
  union { float f; unsigned int u; } v; v.u = ((unsigned int)h) << 16;
  return v.f;
}

#define GLD16(g, s) __builtin_amdgcn_global_load_lds( \
    (const __attribute__((address_space(1))) unsigned int*)(g), \
    (__attribute__((address_space(3))) unsigned int*)(s), 16, 0, 0)

#define SBAR() do{ __builtin_amdgcn_sched_barrier(0); \
                   __builtin_amdgcn_s_barrier(); \
                   __builtin_amdgcn_sched_barrier(0); }while(0)

// ---------------- split fp32 -> (hi, lo) bf16 planes (input) ----------------
__global__ __launch_bounds__(256) void split_k(const float* __restrict__ x,
                                               unsigned short* __restrict__ H,
                                               unsigned short* __restrict__ L, int n4){
  int i = blockIdx.x * 256 + threadIdx.x;
  if (i >= n4) return;
  float4 v = ((const float4*)x)[i];
  unsigned short h0 = f2bf(v.x), h1 = f2bf(v.y), h2 = f2bf(v.z), h3 = f2bf(v.w);
  ushort4 hh = make_ushort4(h0, h1, h2, h3);
  ushort4 ll = make_ushort4(f2bf(v.x - bf2f(h0)), f2bf(v.y - bf2f(h1)),
                            f2bf(v.z - bf2f(h2)), f2bf(v.w - bf2f(h3)));
  ((ushort4*)H)[i] = hh;
  ((ushort4*)L)[i] = ll;
}

// ---------------- fused 7-weight split ----------------
struct WJobs {
  const float* src[7];
  unsigned short* H[7];
  unsigned short* L[7];
  int end4[7];
};
__global__ __launch_bounds__(256) void split_w(WJobs j, int total4){
  int i = blockIdx.x * 256 + threadIdx.x;
  if (i >= total4) return;
  int t = 0, base = 0;
  #pragma unroll
  for (int k = 0; k < 7; k++){
    if (i >= j.end4[k]){ t = k + 1; base = j.end4[k]; }
  }
  int idx = i - base;
  float4 v = ((const float4*)j.src[t])[idx];
  unsigned short h0 = f2bf(v.x), h1 = f2bf(v.y), h2 = f2bf(v.z), h3 = f2bf(v.w);
  ushort4 hh = make_ushort4(h0, h1, h2, h3);
  ushort4 ll = make_ushort4(f2bf(v.x - bf2f(h0)), f2bf(v.y - bf2f(h1)),
                            f2bf(v.z - bf2f(h2)), f2bf(v.w - bf2f(h3)));
  ((ushort4*)j.H[t])[idx] = hh;
  ((ushort4*)j.L[t])[idx] = ll;
}

struct SegDesc {
  const unsigned short* a[6];
  const unsigned short* b[6];
  int tiles[6];
  int stride[6];
};

// =================== gemm256: 8-phase 256x256, counted vmcnt ===================
__global__ __launch_bounds__(512, 1) void gemm256(SegDesc sd, int NT,
    unsigned short* __restrict__ outH, unsigned short* __restrict__ outL,
    float* __restrict__ outF, int Nout, int EPI, int gx,
    const float* __restrict__ lre, const float* __restrict__ lim,
    float2* __restrict__ ends)
{
  __shared__ __align__(16) unsigned short LDS[65536];   // 128 KB

  const int tid = threadIdx.x;
  const int l = tid & 63, w = tid >> 6;
  const int wr = w >> 2, wc = w & 3;
  const int fr = l & 15, fq = l >> 4;

  const int nwg = gridDim.x, bid = blockIdx.x;
  const int q8 = nwg >> 3;
  const int swz = (bid & 7) * q8 + (bid >> 3);
  const int nb = swz % gx, mb = swz / gx;

  const int total_u = 4 * NT;

  auto stage_unit = [&](int u){
    const int Tu = u >> 2, ksu = (u >> 1) & 1, isB = u & 1;
    const unsigned short* p = sd.a[0]; int st = sd.stride[0], kb = 0, cum = 0;
    #pragma unroll
    for (int s = 0; s < 6; s++){
      int tl = sd.tiles[s];
      if (tl && Tu >= cum && Tu < cum + tl){ p = isB ? sd.b[s] : sd.a[s]; st = sd.stride[s]; kb = cum; }
      cum += tl;
    }
    const int kk = ((Tu - kb) << 6) + (ksu << 5);
    const int row0 = (isB ? nb : mb) << 8;
    unsigned short* dst = &LDS[(isB ? 32768 : 0) + (((u >> 1) & 3) << 13)];
    #pragma unroll
    for (int j = 0; j < 2; j++){
      int seg = tid + (j << 9);
      int r = seg >> 2, c4 = seg & 3;
      int sc = (c4 ^ ((r >> 1) & 3)) << 3;
      GLD16(p + (size_t)(row0 + r) * st + kk + sc, dst + seg * 8);
    }
  };

  f32x4 acc[8][4];
  #pragma unroll
  for (int m = 0; m < 8; m++)
    #pragma unroll
    for (int n = 0; n < 4; n++) acc[m][n] = f32x4{0.f, 0.f, 0.f, 0.f};

  for (int u = 0; u < 6 && u < total_u; u++) stage_unit(u);
  if (total_u > 6) asm volatile("s_waitcnt vmcnt(4)" ::: "memory");
  else             asm volatile("s_waitcnt vmcnt(0)" ::: "memory");
  SBAR();

  bf16x8 Bfr[4];
  for (int T = 0; T < NT; T++){
    #pragma unroll
    for (int q = 0; q < 4; q++){
      const int mh = q & 1, ks = q >> 1;
      const int abase = (((2*T + ks) & 3) << 13);
      const int bbase = 32768 + abase;
      bf16x8 Afr[4];
      #pragma unroll
      for (int m = 0; m < 4; m++){
        int row = wr*128 + mh*64 + m*16 + fr;
        Afr[m] = *(const bf16x8*)&LDS[abase + row*32 + ((fq ^ ((row>>1)&3)) << 3)];
      }
      if (mh == 0){
        #pragma unroll
        for (int n = 0; n < 4; n++){
          int row = wc*64 + n*16 + fr;
          Bfr[n] = *(const bf16x8*)&LDS[bbase + row*32 + ((fq ^ ((row>>1)&3)) << 3)];
        }
      }
      int u = 4*T + q + 6;
      if (u < total_u) stage_unit(u);
      if (q == 1){
        if (T <= NT-2) asm volatile("s_waitcnt vmcnt(4)" ::: "memory");
      } else if (q == 3){
        if (T < NT-2)       asm volatile("s_waitcnt vmcnt(4)" ::: "memory");
        else if (T == NT-2) asm volatile("s_waitcnt vmcnt(0)" ::: "memory");
      }
      SBAR();
      __builtin_amdgcn_s_setprio(1);
      #pragma unroll
      for (int m = 0; m < 4; m++)
        #pragma unroll
        for (int n = 0; n < 4; n++)
          acc[mh*4+m][n] = __builtin_amdgcn_mfma_f32_16x16x32_bf16(Afr[m], Bfr[n], acc[mh*4+m][n], 0, 0, 0);
      __builtin_amdgcn_s_setprio(0);
      SBAR();
    }
  }

  // ---- epilogue: acc -> LDS f32 half [128][256]; optional fused chunk-ends ----
  float* fl = (float*)LDS;
  #pragma unroll
  for (int h = 0; h < 2; h++){
    if (wr == h){
      #pragma unroll
      for (int mf = 0; mf < 8; mf++)
        #pragma unroll
        for (int n = 0; n < 4; n++)
          #pragma unroll
          for (int j = 0; j < 4; j++)
            fl[(mf*16 + fq*4 + j)*256 + wc*64 + n*16 + fr] = acc[mf][n][j];
    }
    __syncthreads();
    if (ends){
      int s = tid & 255, cp = tid >> 8;
      int b = mb >> 4, chunk = ((mb & 15) << 2) + (h << 1) + cp;
      float lr = lre[s], li = lim[s];
      float hr = 0.f, hi2 = 0.f;
      for (int t = 0; t < 64; t++){
        float x = fl[(cp*64 + t)*256 + s];
        float nr = fmaf(lr, hr, fmaf(-li, hi2, x));
        float ni = fmaf(lr, hi2, li * hr);
        hr = nr; hi2 = ni;
      }
      ends[((size_t)(b*NCH + chunk))*SS + s] = make_float2(hr, hi2);
    }
    #pragma unroll
    for (int it = 0; it < 8; it++){
      int task = tid + (it << 9);
      int rl = task >> 5, cg = task & 31;
      float4 v0 = *(const float4*)&fl[rl*256 + cg*8];
      float4 v1 = *(const float4*)&fl[rl*256 + cg*8 + 4];
      size_t o = (size_t)(mb*256 + h*128 + rl) * Nout + nb*256 + cg*8;
      if (EPI == 0){
        *(float4*)(outF + o)     = v0;
        *(float4*)(outF + o + 4) = v1;
      } else {
        float xv[8] = {v0.x,v0.y,v0.z,v0.w,v1.x,v1.y,v1.z,v1.w};
        union { unsigned short us[8]; uint4 v; } ph, pl;
        #pragma unroll
        for (int e = 0; e < 8; e++){
          float x = xv[e];
          if (EPI == 2)      x = x / (1.f + __expf(-x));   // silu
          else if (EPI == 3) x = fmaxf(x, 0.f);            // relu
          ph.us[e] = f2bf(x);
          pl.us[e] = f2bf(x - bf2f(ph.us[e]));
        }
        *(uint4*)(outH + o) = ph.v;
        if (outL) *(uint4*)(outL + o) = pl.v;
      }
    }
    __syncthreads();
  }
}

// =================== gemm_split: 128x128 2-phase (N=128 ops) ===================
// Terms per source via flags: bit0 = al*bh, bit1 = ah*bl (ah*bh always).
__global__ __launch_bounds__(256, 2) void gemm_split(
    const unsigned short* __restrict__ AH1, const unsigned short* __restrict__ AL1,
    const unsigned short* __restrict__ BH1, const unsigned short* __restrict__ BL1, int K1, int f1,
    const unsigned short* __restrict__ AH2, const unsigned short* __restrict__ AL2,
    const unsigned short* __restrict__ BH2, const unsigned short* __restrict__ BL2, int K2, int f2,
    unsigned short* __restrict__ outH, unsigned short* __restrict__ outL,
    float* __restrict__ outF, int Nout, int EPI)
{
  __shared__ __align__(16) unsigned short SM[32768];   // 64 KB
  unsigned short* Ah = SM;            // [2][4096]
  unsigned short* Al = SM + 8192;
  unsigned short* Bh = SM + 16384;
  unsigned short* Bl = SM + 24576;

  const int tid = threadIdx.x;
  const int mb = blockIdx.x, nb = blockIdx.y;
  const int l = tid & 63, w = tid >> 6;
  const int wr = w >> 1, wc = w & 1;
  const int fr = l & 15, fq = l >> 4;

  f32x4 acc[4][4];
  #pragma unroll
  for (int m = 0; m < 4; m++)
    #pragma unroll
    for (int n = 0; n < 4; n++) acc[m][n] = f32x4{0.f, 0.f, 0.f, 0.f};

  const int nkt = (K1 + K2) >> 5;

  auto STAGE = [&](int buf, int kt){
    const int k0 = kt << 5;
    const unsigned short *aH, *aL, *bH, *bL; int st, kk, flg;
    if (k0 < K1){ aH = AH1; aL = AL1; bH = BH1; bL = BL1; st = K1; kk = k0; flg = f1; }
    else        { aH = AH2; aL = AL2; bH = BH2; bL = BL2; st = K2; kk = k0 - K1; flg = f2; }
    #pragma unroll
    for (int it = 0; it < 2; it++){
      int seg = tid + it * 256;
      int r = seg >> 2, c4 = seg & 3;
      int sc = (c4 ^ (r & 3)) << 3;
      size_t go = (size_t)(mb*128 + r) * st + kk + sc;
      size_t gb = (size_t)(nb*128 + r) * st + kk + sc;
      int lo = buf*4096 + r*32 + c4*8;
      GLD16(aH + go, Ah + lo);
      if (flg & 1) GLD16(aL + go, Al + lo);
      GLD16(bH + gb, Bh + lo);
      if (flg & 2) GLD16(bL + gb, Bl + lo);
    }
  };

  STAGE(0, 0);
  __syncthreads();

  for (int kt = 0; kt < nkt; kt++){
    const int cur = kt & 1;
    const int flg = ((kt << 5) < K1) ? f1 : f2;
    if (kt + 1 < nkt) STAGE(cur ^ 1, kt + 1);

    bf16x8 a_h[4], a_l[4], b_h[4], b_l[4];
    #pragma unroll
    for (int m = 0; m < 4; m++){
      int lra = wr*64 + m*16 + fr;
      int ra = cur*4096 + lra*32 + ((fq ^ (lra & 3)) << 3);
      a_h[m] = *(const bf16x8*)&Ah[ra];
      if (flg & 1) a_l[m] = *(const bf16x8*)&Al[ra];
      int lrb = wc*64 + m*16 + fr;
      int rb = cur*4096 + lrb*32 + ((fq ^ (lrb & 3)) << 3);
      b_h[m] = *(const bf16x8*)&Bh[rb];
      if (flg & 2) b_l[m] = *(const bf16x8*)&Bl[rb];
    }
    __builtin_amdgcn_s_setprio(1);
    #pragma unroll
    for (int m = 0; m < 4; m++)
      #pragma unroll
      for (int n = 0; n < 4; n++)
        acc[m][n] = __builtin_amdgcn_mfma_f32_16x16x32_bf16(a_h[m], b_h[n], acc[m][n], 0, 0, 0);
    if (flg & 1)
      #pragma unroll
      for (int m = 0; m < 4; m++)
        #pragma unroll
        for (int n = 0; n < 4; n++)
          acc[m][n] = __builtin_amdgcn_mfma_f32_16x16x32_bf16(a_l[m], b_h[n], acc[m][n], 0, 0, 0);
    if (flg & 2)
      #pragma unroll
      for (int m = 0; m < 4; m++)
        #pragma unroll
        for (int n = 0; n < 4; n++)
          acc[m][n] = __builtin_amdgcn_mfma_f32_16x16x32_bf16(a_h[m], b_l[n], acc[m][n], 0, 0, 0);
    __builtin_amdgcn_s_setprio(0);

    __syncthreads();
  }

  // ---- coalesced epilogue via LDS (128x128 f32 = 64 KB) ----
  float* fl = (float*)SM;
  #pragma unroll
  for (int m = 0; m < 4; m++)
    #pragma unroll
    for (int n = 0; n < 4; n++)
      #pragma unroll
      for (int j = 0; j < 4; j++)
        fl[(wr*64 + m*16 + fq*4 + j)*128 + wc*64 + n*16 + fr] = acc[m][n][j];
  __syncthreads();
  #pragma unroll
  for (int it = 0; it < 8; it++){
    int task = tid + (it << 8);
    int rl = task >> 4, cg = task & 15;
    float4 v0 = *(const float4*)&fl[rl*128 + cg*8];
    float4 v1 = *(const float4*)&fl[rl*128 + cg*8 + 4];
    size_t o = (size_t)(mb*128 + rl) * Nout + nb*128 + cg*8;
    if (EPI == 0){
      *(float4*)(outF + o)     = v0;
      *(float4*)(outF + o + 4) = v1;
    } else {
      float xv[8] = {v0.x,v0.y,v0.z,v0.w,v1.x,v1.y,v1.z,v1.w};
      union { unsigned short us[8]; uint4 v; } ph, pl;
      #pragma unroll
      for (int e = 0; e < 8; e++){
        float x = xv[e];
        if (EPI == 2)      x = x / (1.f + __expf(-x));
        else if (EPI == 3) x = fmaxf(x, 0.f);
        ph.us[e] = f2bf(x);
        pl.us[e] = f2bf(x - bf2f(ph.us[e]));
      }
      *(uint4*)(outH + o) = ph.v;
      if (outL) *(uint4*)(outL + o) = pl.v;
    }
  }
}

// ---------------- scan carries ----------------
__global__ __launch_bounds__(256) void scan_carries(const float2* __restrict__ ends,
                                                    const float* __restrict__ lre,
                                                    const float* __restrict__ lim,
                                                    float2* __restrict__ carryin){
  const int idx = blockIdx.x * 256 + threadIdx.x;
  const int b = idx >> 8;
  const int s = idx & 255;
  float pr = lre[s], pi = lim[s];
  #pragma unroll
  for (int q = 0; q < 6; q++){
    float nr = pr*pr - pi*pi;
    float ni = 2.f * pr * pi;
    pr = nr; pi = ni;
  }
  float hr = 0.f, hi = 0.f;
  for (int c = 0; c < NCH; c++){
    size_t o = ((size_t)b*NCH + c)*SS + s;
    carryin[o] = make_float2(hr, hi);
    float2 e = ends[o];
    float nr = fmaf(pr, hr, fmaf(-pi, hi, e.x));
    float ni = fmaf(pr, hi, fmaf(pi, hr, e.y));
    hr = nr; hi = ni;
  }
}

// ---------------- scan apply: vectorized, RehH (bf16) only ----------------
__global__ __launch_bounds__(256) void scan_apply_v(
    const unsigned short* __restrict__ buH, const unsigned short* __restrict__ buL,
    const float* __restrict__ lre, const float* __restrict__ lim,
    const float2* __restrict__ carryin, unsigned short* __restrict__ RehH){
  const int tid = threadIdx.x;
  const int grp = tid >> 6, ln = tid & 63;
  const int chunk = blockIdx.x * 4 + grp;         // 0..1023
  const int b = chunk >> 6, ch = chunk & 63;
  const int s0 = ln * 4;
  float lr[4], li[4], hr[4], hi[4];
  #pragma unroll
  for (int e = 0; e < 4; e++){ lr[e] = lre[s0+e]; li[e] = lim[s0+e]; }
  const float2* ci = &carryin[((size_t)(b*NCH + ch))*SS + s0];
  #pragma unroll
  for (int e = 0; e < 4; e++){ hr[e] = ci[e].x; hi[e] = ci[e].y; }
  const size_t rbase = ((size_t)b*TT + (size_t)ch*CLEN)*SS + s0;
  for (int t = 0; t < CLEN; t++){
    uint2 hv = *(const uint2*)(buH + rbase + (size_t)t*SS);
    uint2 lv = *(const uint2*)(buL + rbase + (size_t)t*SS);
    const unsigned short* hs = (const unsigned short*)&hv;
    const unsigned short* ls = (const unsigned short*)&lv;
    uint2 ov; unsigned short* os = (unsigned short*)&ov;
    #pragma unroll
    for (int e = 0; e < 4; e++){
      float x = bf2f(hs[e]) + bf2f(ls[e]);
      float nr = fmaf(lr[e], hr[e], fmaf(-li[e], hi[e], x));
      float ni = fmaf(lr[e], hi[e], li[e] * hr[e]);
      hr[e] = nr; hi[e] = ni;
      os[e] = f2bf(nr);
    }
    *(uint2*)(RehH + rbase + (size_t)t*SS) = ov;
  }
}

// ---------------- host-side segment builders ----------------
static void seg_clear(SegDesc& sd){
  for (int i = 0; i < 6; i++){ sd.a[i]=nullptr; sd.b[i]=nullptr; sd.tiles[i]=0; sd.stride[i]=0; }
}
static int seg_add(SegDesc& sd, int at,
                   const unsigned short* a, const unsigned short* b, int K){
  sd.a[at]=a; sd.b[at]=b; sd.tiles[at]=K>>6; sd.stride[at]=K;
  return K>>6;
}

extern "C" void kernel_launch(void* const* d_in, const int* in_sizes, int n_in,
                              void* d_out, int out_size, void* d_ws, size_t ws_size,
                              hipStream_t stream){
  const float* inp = (const float*)d_in[0];
  const float* lre = (const float*)d_in[1];
  const float* lim = (const float*)d_in[2];
  const float* Bm  = (const float*)d_in[3];
  const float* Cm  = (const float*)d_in[4];
  const float* Dm  = (const float*)d_in[5];
  const float* W1  = (const float*)d_in[6];
  const float* W2  = (const float*)d_in[7];
  const float* W3  = (const float*)d_in[8];
  const float* Wl  = (const float*)d_in[9];
  float* out = (float*)d_out;

  char* ws = (char*)d_ws;
  size_t off = 0;
  auto alloc = [&](size_t bytes)->char*{
    char* p = ws + off; off += (bytes + 255) & ~(size_t)255; return p;
  };
  // ---- region-reused workspace plan (~171 MB, proven-safe < 207 MB) ----
  unsigned short* inH  = (unsigned short*)alloc((size_t)BT*UU*2);   // 16.8 MB (live all)
  unsigned short* inL  = (unsigned short*)alloc((size_t)BT*UU*2);   // 16.8 MB (live all)
  char* Rbu = alloc((size_t)BT*SS*2*2);                             // 67.1 MB: buH+buL -> z1H
  unsigned short* buH = (unsigned short*)Rbu;
  unsigned short* buL = (unsigned short*)(Rbu + (size_t)BT*SS*2);
  unsigned short* z1H = (unsigned short*)Rbu;                       // 64 MB, after bu dead
  char* R2 = alloc((size_t)BT*HH*2);                                // 64 MB: RehH+yH -> z2H
  unsigned short* RehH = (unsigned short*)R2;                       // 33.6 MB
  unsigned short* yH   = (unsigned short*)(R2 + (size_t)BT*SS*2);   // 16.8 MB
  unsigned short* z2H  = (unsigned short*)R2;                       // 64 MB, after Reh/y dead
  unsigned short* BwH = (unsigned short*)alloc((size_t)SS*UU*2);
  unsigned short* BwL = (unsigned short*)alloc((size_t)SS*UU*2);
  unsigned short* CH_ = (unsigned short*)alloc((size_t)OO*SS*2);
  unsigned short* CL_ = (unsigned short*)alloc((size_t)OO*SS*2);
  unsigned short* DH_ = (unsigned short*)alloc((size_t)OO*UU*2);
  unsigned short* DL_ = (unsigned short*)alloc((size_t)OO*UU*2);
  unsigned short* W1H = (unsigned short*)alloc((size_t)HH*OO*2);
  unsigned short* W1L = (unsigned short*)alloc((size_t)HH*OO*2);
  unsigned short* W2H = (unsigned short*)alloc((size_t)HH*HH*2);
  unsigned short* W2L = (unsigned short*)alloc((size_t)HH*HH*2);
  unsigned short* W3H = (unsigned short*)alloc((size_t)OO*HH*2);
  unsigned short* W3L = (unsigned short*)alloc((size_t)OO*HH*2);
  unsigned short* WlH = (unsigned short*)alloc((size_t)OO*UU*2);
  unsigned short* WlL = (unsigned short*)alloc((size_t)OO*UU*2);
  float2* ends    = (float2*)alloc((size_t)BSZ*NCH*SS*8);
  float2* carryin = (float2*)alloc((size_t)BSZ*NCH*SS*8);
  if (off > ws_size) return;

  // ---- splits ----
  split_k<<<(BT*UU/4 + 255)/256, 256, 0, stream>>>(inp, inH, inL, BT*UU/4);
  {
    WJobs j;
    const float* srcs[7] = {Bm, Cm, Dm, W1, W2, W3, Wl};
    unsigned short* Hs[7] = {BwH, CH_, DH_, W1H, W2H, W3H, WlH};
    unsigned short* Ls[7] = {BwL, CL_, DL_, W1L, W2L, W3L, WlL};
    int n4s[7] = {SS*UU/4, OO*SS/4, OO*UU/4, HH*OO/4, HH*HH/4, OO*HH/4, OO*UU/4};
    int cum = 0;
    for (int k = 0; k < 7; k++){
      j.src[k] = srcs[k]; j.H[k] = Hs[k]; j.L[k] = Ls[k];
      cum += n4s[k]; j.end4[k] = cum;
    }
    split_w<<<(cum + 255)/256, 256, 0, stream>>>(j, cum);
  }

  SegDesc sd; int NT;

  // ---- bu = input @ B^T (3-term) -> buH/buL + fused chunk-end scans ----
  seg_clear(sd);
  NT  = seg_add(sd, 0, inH, BwH, UU);
  NT += seg_add(sd, 1, inH, BwL, UU);
  NT += seg_add(sd, 2, inL, BwH, UU);          // NT = 6
  gemm256<<<(BT/256)*(SS/256), 512, 0, stream>>>(sd, NT, buH, buL, nullptr, SS, 1, SS/256,
                                                 lre, lim, ends);

  // ---- cross-chunk carries ----
  scan_carries<<<(BSZ*SS)/256, 256, 0, stream>>>(ends, lre, lim, carryin);

  // ---- scan apply -> RehH (bf16 only) ----
  scan_apply_v<<<BSZ*NCH/4, 256, 0, stream>>>(buH, buL, lre, lim, carryin, RehH);

  // ---- y = Reh@C^T (2-term: C hi+lo) + in@D^T (3-term); yH only ----
  gemm_split<<<dim3(BT/128, OO/128), 256, 0, stream>>>(
      RehH, RehH, CH_, CL_, SS, 2,
      inH,  inL,  DH_, DL_, UU, 3,
      yH, nullptr, nullptr, OO, 1);

  // ---- z1 = silu(y @ W1^T): 1-term, NT=2 (writes over dead bu region) ----
  seg_clear(sd);
  NT = seg_add(sd, 0, yH, W1H, OO);            // NT = 2
  gemm256<<<(BT/256)*(HH/256), 512, 0, stream>>>(sd, NT, z1H, nullptr, nullptr, HH, 2, HH/256,
                                                 nullptr, nullptr, nullptr);

  // ---- z2 = relu(z1 @ W2^T): 1-term, NT=8 (writes over dead Reh/y region) ----
  seg_clear(sd);
  NT = seg_add(sd, 0, z1H, W2H, HH);           // NT = 8
  gemm256<<<(BT/256)*(HH/256), 512, 0, stream>>>(sd, NT, z2H, nullptr, nullptr, HH, 3, HH/256,
                                                 nullptr, nullptr, nullptr);

  // ---- out = z2 @ W3^T (2-term: W3 hi+lo) + in @ Wlin^T (3-term), fp32 ----
  gemm_split<<<dim3(BT/128, OO/128), 256, 0, stream>>>(
      z2H, z2H, W3H, W3L, HH, 2,
      inH, inL, WlH, WlL, UU, 3,
      nullptr, nullptr, out, OO, 0);
}